// Round 1
// baseline (5555.195 us; speedup 1.0000x reference)
//
#include <hip/hip_runtime.h>

typedef unsigned long long u64;

#define Bsz 8
#define Npts 32
#define Kb 5
#define Mpc 4096
#define NCAD 2048
#define NSTEPS 20

// consts (doubles) layout
#define CD_GI 0      // 25
#define CD_BMEAN 25  // 15
#define CD_WD 40     // 32
#define CD_WSUM 72
#define CD_LAMK 74
#define CD_BC 80     // 480
// sav per-b layout (doubles), stride 512
#define SV_YC 0      // 96
#define SV_B1 96     // 3 x 96
#define SV_R1 384    // 3 x 9
#define SV_U1 411    // 3 x 22 (U9,s3,V9,d1)
#define SV_C2 477    // 5
#define SV_T 482     // 3
#define SV_STRIDE 512
#define SV_USTR 22

// ---------------- fp64 helpers (single-thread) ----------------
__device__ inline double det3d(const double M[3][3]){
  return M[0][0]*(M[1][1]*M[2][2]-M[1][2]*M[2][1])
       - M[0][1]*(M[1][0]*M[2][2]-M[1][2]*M[2][0])
       + M[0][2]*(M[1][0]*M[2][1]-M[1][1]*M[2][0]);
}

#define JROT(p,q,u) { \
  double apq=A[p][q]; \
  if (fabs(apq)>1e-300){ \
    double theta=(A[q][q]-A[p][p])/(2.0*apq); \
    double tt=(theta>=0.0)?1.0/(theta+sqrt(1.0+theta*theta)):1.0/(theta-sqrt(1.0+theta*theta)); \
    double cc=1.0/sqrt(1.0+tt*tt), ssn=tt*cc; \
    double app=A[p][p], aqq=A[q][q]; \
    A[p][p]=app-tt*apq; A[q][q]=aqq+tt*apq; A[p][q]=0.0; A[q][p]=0.0; \
    double aup=A[u][p], auq=A[u][q]; \
    A[u][p]=cc*aup-ssn*auq; A[p][u]=A[u][p]; \
    A[u][q]=ssn*aup+cc*auq; A[q][u]=A[u][q]; \
    for (int i_=0;i_<3;i_++){ double vip=V[i_][p], viq=V[i_][q]; V[i_][p]=cc*vip-ssn*viq; V[i_][q]=ssn*vip+cc*viq; } \
  } }

__device__ void svd3(const double H[3][3], double U[3][3], double s[3], double V[3][3], double* dsg)
{
  double A[3][3];
  for (int i=0;i<3;i++) for (int j=0;j<3;j++){
    double a=0.0;
    for (int k=0;k<3;k++) a += H[k][i]*H[k][j];
    A[i][j]=a;
  }
  V[0][0]=1;V[0][1]=0;V[0][2]=0; V[1][0]=0;V[1][1]=1;V[1][2]=0; V[2][0]=0;V[2][1]=0;V[2][2]=1;
  for (int sweep=0; sweep<8; ++sweep){
    double off=fabs(A[0][1])+fabs(A[0][2])+fabs(A[1][2]);
    double dia=fabs(A[0][0])+fabs(A[1][1])+fabs(A[2][2]);
    if (off <= 1e-14*dia + 1e-300) break;
    JROT(0,1,2)
    JROT(0,2,1)
    JROT(1,2,0)
  }
  double e0=A[0][0], e1=A[1][1], e2=A[2][2];
  if (e0<e1){ double t=e0;e0=e1;e1=t; for(int i=0;i<3;i++){double tv=V[i][0];V[i][0]=V[i][1];V[i][1]=tv;} }
  if (e0<e2){ double t=e0;e0=e2;e2=t; for(int i=0;i<3;i++){double tv=V[i][0];V[i][0]=V[i][2];V[i][2]=tv;} }
  if (e1<e2){ double t=e1;e1=e2;e2=t; for(int i=0;i<3;i++){double tv=V[i][1];V[i][1]=V[i][2];V[i][2]=tv;} }
  for (int c=0;c<3;c++){
    double u0=H[0][0]*V[0][c]+H[0][1]*V[1][c]+H[0][2]*V[2][c];
    double u1=H[1][0]*V[0][c]+H[1][1]*V[1][c]+H[1][2]*V[2][c];
    double u2=H[2][0]*V[0][c]+H[2][1]*V[1][c]+H[2][2]*V[2][c];
    double nr=sqrt(u0*u0+u1*u1+u2*u2);
    s[c]=nr;
    double inv=(nr>1e-300)?1.0/nr:0.0;
    U[0][c]=u0*inv; U[1][c]=u1*inv; U[2][c]=u2*inv;
  }
  if (s[2] <= 1e-12*s[0]){
    U[0][2]=U[1][0]*U[2][1]-U[2][0]*U[1][1];
    U[1][2]=U[2][0]*U[0][1]-U[0][0]*U[2][1];
    U[2][2]=U[0][0]*U[1][1]-U[1][0]*U[0][1];
  }
  double dd=det3d(U)*det3d(V);
  *dsg = (dd>=0.0)?1.0:-1.0;
}

// VJP of R = U diag(1,1,d) V^T  (det-chain terms cancel in antisymmetrization)
__device__ void proc_bwd(const double dRm[3][3], const double* sv, double dH[3][3])
{
  double U[3][3],V[3][3],s[3],dsg;
  for (int i=0;i<3;i++) for (int j=0;j<3;j++){ U[i][j]=sv[i*3+j]; V[i][j]=sv[12+i*3+j]; }
  s[0]=sv[9]; s[1]=sv[10]; s[2]=sv[11];
  dsg=sv[21];
  double A0[3][3];
  for (int a=0;a<3;a++) for (int c=0;c<3;c++){
    double x=0.0;
    for (int i=0;i<3;i++) for (int j=0;j<3;j++) x += U[i][a]*dRm[i][j]*V[j][c];
    A0[a][c]=x;
  }
  double D[3]={1.0,1.0,dsg};
  double Q[3][3]={{0,0,0},{0,0,0},{0,0,0}};
  for (int i=0;i<3;i++) for (int j=0;j<3;j++){
    if (i==j) continue;
    double Muu=A0[i][j]*D[j]-D[i]*A0[j][i];
    double Mvv=A0[j][i]*D[j]-D[i]*A0[i][j];
    double den=s[j]*s[j]-s[i]*s[i];
    if (fabs(den)<1e-30) den=(den>=0.0?1e-30:-1e-30);
    Q[i][j]=(Muu*s[j]+s[i]*Mvv)/den;
  }
  for (int i=0;i<3;i++) for (int j=0;j<3;j++){
    double x=0.0;
    for (int a=0;a<3;a++) for (int c=0;c<3;c++) x += U[i][a]*Q[a][c]*V[j][c];
    dH[i][j]=x;
  }
}

// PACE forward (thread-0 serial, fp64), saving all backward intermediates
__device__ void pace_forward(const float* kp_b, const float* corr_b, const double* consts,
                             double* yc, double* bb, double* yr, double* sav,
                             double R3[3][3], double tvec[3], double c2out[5])
{
  const double* Gi    = consts+CD_GI;
  const double* Bmean = consts+CD_BMEAN;
  const double* wd    = consts+CD_WD;
  const double* Bc    = consts+CD_BC;
  double wsum = consts[CD_WSUM];
  double lamK = consts[CD_LAMK];

  double ymean[3];
  for (int i=0;i<3;i++){
    double a=0.0;
    for (int n=0;n<Npts;n++) a += ((double)kp_b[i*Npts+n]+(double)corr_b[i*Npts+n])*wd[n];
    ymean[i]=a/wsum;
  }
  for (int i=0;i<3;i++) for (int n=0;n<Npts;n++)
    yc[i*Npts+n]=(double)kp_b[i*Npts+n]+(double)corr_b[i*Npts+n]-ymean[i];
  for (int e=0;e<96;e++) sav[SV_YC+e]=yc[e];

  double c[Kb];
  for (int k=0;k<Kb;k++) c[k]=1.0/(double)Kb;

  for (int r=0;r<3;r++){
    for (int i=0;i<3;i++) for (int n=0;n<Npts;n++){
      double a=0.0;
      for (int k=0;k<Kb;k++) a += c[k]*Bc[(k*3+i)*Npts+n];
      bb[i*Npts+n]=a;
    }
    double H[3][3];
    for (int i=0;i<3;i++) for (int j=0;j<3;j++){
      double a=0.0;
      for (int n=0;n<Npts;n++) a += yc[i*Npts+n]*wd[n]*bb[j*Npts+n];
      H[i][j]=a;
    }
    double U[3][3],V[3][3],s[3],dsg;
    svd3(H,U,s,V,&dsg);
    double R[3][3];
    for (int i=0;i<3;i++) for (int j=0;j<3;j++)
      R[i][j]=U[i][0]*V[j][0]+U[i][1]*V[j][1]+dsg*U[i][2]*V[j][2];

    // save
    {
      double* pb = sav + SV_B1 + r*96;
      for (int e=0;e<96;e++) pb[e]=bb[e];
      double* pr = sav + SV_R1 + r*9;
      for (int i=0;i<3;i++) for (int j=0;j<3;j++) pr[i*3+j]=R[i][j];
      double* pu = sav + SV_U1 + r*SV_USTR;
      for (int i=0;i<3;i++) for (int j=0;j<3;j++){ pu[i*3+j]=U[i][j]; pu[12+i*3+j]=V[i][j]; }
      pu[9]=s[0]; pu[10]=s[1]; pu[11]=s[2];
      pu[21]=dsg;
    }

    if (r<2){
      for (int i=0;i<3;i++) for (int n=0;n<Npts;n++)
        yr[i*Npts+n]=R[0][i]*yc[0*Npts+n]+R[1][i]*yc[1*Npts+n]+R[2][i]*yc[2*Npts+n];
      double h[Kb];
      for (int k=0;k<Kb;k++){
        double a=0.0;
        for (int i=0;i<3;i++) for (int n=0;n<Npts;n++) a += Bc[(k*3+i)*Npts+n]*wd[n]*yr[i*Npts+n];
        h[k]=a+lamK;
      }
      double cn[Kb];
      for (int k=0;k<Kb;k++){
        double a=0.0;
        for (int l=0;l<Kb;l++) a += Gi[k*Kb+l]*h[l];
        cn[k]=a;
      }
      for (int k=0;k<Kb;k++) c[k]=cn[k];
    } else {
      for (int i=0;i<3;i++) for (int j=0;j<3;j++) R3[i][j]=R[i][j];
    }
  }
  double bmean[3];
  for (int i=0;i<3;i++){
    double a=0.0;
    for (int k=0;k<Kb;k++) a += c[k]*Bmean[k*3+i];
    bmean[i]=a;
  }
  for (int i=0;i<3;i++)
    tvec[i]=ymean[i]-(R3[i][0]*bmean[0]+R3[i][1]*bmean[1]+R3[i][2]*bmean[2]);
  for (int k=0;k<Kb;k++){ c2out[k]=c[k]; sav[SV_C2+k]=c[k]; }
  for (int i=0;i<3;i++) sav[SV_T+i]=tvec[i];
}

// ---------------- kernels ----------------
__global__ void k_init(const float* __restrict__ corr0, const float* __restrict__ mkp,
                       const float* __restrict__ w, const float* __restrict__ lamp,
                       float* __restrict__ corr, double* __restrict__ consts)
{
  int tid=threadIdx.x;
  for (int e=tid;e<Bsz*3*Npts;e+=blockDim.x) corr[e]=corr0[e];
  if (tid!=0) return;
  double wsum=0.0;
  for (int n=0;n<Npts;n++){ double wv=(double)w[n]; consts[CD_WD+n]=wv; wsum+=wv; }
  consts[CD_WSUM]=wsum;
  double lam=(double)lamp[0];
  consts[CD_LAMK]=lam/(double)Kb;
  for (int k=0;k<Kb;k++) for (int i=0;i<3;i++){
    double a=0.0;
    for (int n=0;n<Npts;n++) a += (double)mkp[(k*3+i)*Npts+n]*consts[CD_WD+n];
    consts[CD_BMEAN+k*3+i]=a/wsum;
  }
  for (int k=0;k<Kb;k++) for (int i=0;i<3;i++) for (int n=0;n<Npts;n++)
    consts[CD_BC+(k*3+i)*Npts+n]=(double)mkp[(k*3+i)*Npts+n]-consts[CD_BMEAN+k*3+i];
  double G[Kb][Kb];
  for (int k=0;k<Kb;k++) for (int l=0;l<Kb;l++){
    double a=0.0;
    for (int i=0;i<3;i++) for (int n=0;n<Npts;n++)
      a += consts[CD_BC+(k*3+i)*Npts+n]*consts[CD_WD+n]*consts[CD_BC+(l*3+i)*Npts+n];
    G[k][l]=a+((k==l)?lam:0.0);
  }
  // Gauss-Jordan inverse with partial pivoting
  double Aug[Kb][2*Kb];
  for (int i=0;i<Kb;i++) for (int j=0;j<Kb;j++){ Aug[i][j]=G[i][j]; Aug[i][Kb+j]=(i==j)?1.0:0.0; }
  for (int col=0;col<Kb;col++){
    int piv=col; double best=fabs(Aug[col][col]);
    for (int r=col+1;r<Kb;r++) if (fabs(Aug[r][col])>best){best=fabs(Aug[r][col]);piv=r;}
    if (piv!=col) for (int j=0;j<2*Kb;j++){ double t=Aug[col][j]; Aug[col][j]=Aug[piv][j]; Aug[piv][j]=t; }
    double ip=1.0/Aug[col][col];
    for (int j=0;j<2*Kb;j++) Aug[col][j]*=ip;
    for (int r=0;r<Kb;r++) if (r!=col){
      double f=Aug[r][col];
      for (int j=0;j<2*Kb;j++) Aug[r][j]-=f*Aug[col][j];
    }
  }
  for (int k=0;k<Kb;k++) for (int l=0;l<Kb;l++) consts[CD_GI+k*Kb+l]=Aug[k][Kb+l];
}

__global__ void k_pace_model(const float* __restrict__ kp, const float* __restrict__ cad,
                             const float* __restrict__ corr, const double* __restrict__ consts,
                             double* __restrict__ sav, float* __restrict__ model,
                             u64* __restrict__ minbuf)
{
  int b=blockIdx.x;
  __shared__ double s_yc[96], s_bb[96], s_yr[96];
  __shared__ float sR[9], sT[3], sC[Kb];
  if (threadIdx.x==0){
    double R3[3][3], tv[3], c2[Kb];
    pace_forward(kp+b*96, corr+b*96, consts, s_yc, s_bb, s_yr, sav+(size_t)b*SV_STRIDE, R3, tv, c2);
    for (int i=0;i<3;i++){ sT[i]=(float)tv[i]; for (int j=0;j<3;j++) sR[i*3+j]=(float)R3[i][j]; }
    for (int k=0;k<Kb;k++) sC[k]=(float)c2[k];
  }
  __syncthreads();
  for (int j=threadIdx.x;j<NCAD;j+=blockDim.x){
    float m0v[3];
    for (int l=0;l<3;l++){
      float a=0.f;
      for (int k=0;k<Kb;k++) a += sC[k]*cad[(k*3+l)*NCAD+j];
      m0v[l]=a;
    }
    for (int i=0;i<3;i++)
      model[((size_t)b*3+i)*NCAD+j]=sR[i*3+0]*m0v[0]+sR[i*3+1]*m0v[1]+sR[i*3+2]*m0v[2]+sT[i];
  }
  for (int i=threadIdx.x;i<Mpc;i+=blockDim.x) minbuf[(size_t)b*Mpc+i]=~0ull;
}

__global__ void k_chamfer(const float* __restrict__ pc, const float* __restrict__ model,
                          u64* __restrict__ minbuf)
{
  int b=blockIdx.z;
  int jbase=blockIdx.y*512;
  int ibase=blockIdx.x*512;
  __shared__ float mx[512],my[512],mz[512];
  for (int t=threadIdx.x;t<512;t+=blockDim.x){
    mx[t]=model[((size_t)b*3+0)*NCAD+jbase+t];
    my[t]=model[((size_t)b*3+1)*NCAD+jbase+t];
    mz[t]=model[((size_t)b*3+2)*NCAD+jbase+t];
  }
  __syncthreads();
  int i0=ibase+threadIdx.x, i1=i0+256;
  float x0=pc[((size_t)b*3+0)*Mpc+i0], y0=pc[((size_t)b*3+1)*Mpc+i0], z0=pc[((size_t)b*3+2)*Mpc+i0];
  float x1=pc[((size_t)b*3+0)*Mpc+i1], y1=pc[((size_t)b*3+1)*Mpc+i1], z1=pc[((size_t)b*3+2)*Mpc+i1];
  float b0=3.4e38f, b1v=3.4e38f;
  int j0=0, j1=0;
  #pragma unroll 4
  for (int j=0;j<512;j++){
    float ax=mx[j], ay=my[j], az=mz[j];
    float dx=x0-ax, dy=y0-ay, dz=z0-az;
    float d2=dx*dx+dy*dy+dz*dz;
    if (d2<b0){b0=d2;j0=j;}
    dx=x1-ax; dy=y1-ay; dz=z1-az;
    d2=dx*dx+dy*dy+dz*dz;
    if (d2<b1v){b1v=d2;j1=j;}
  }
  atomicMin(&minbuf[(size_t)b*Mpc+i0], ((u64)__float_as_uint(b0)<<32)|(u64)(unsigned)(jbase+j0));
  atomicMin(&minbuf[(size_t)b*Mpc+i1], ((u64)__float_as_uint(b1v)<<32)|(u64)(unsigned)(jbase+j1));
}

__global__ void k_grad(const float* __restrict__ pc, const float* __restrict__ cad,
                       const float* __restrict__ model, const u64* __restrict__ minbuf,
                       const double* __restrict__ consts, const double* __restrict__ sav_all,
                       float* __restrict__ corr)
{
  int b=blockIdx.x, tid=threadIdx.x;
  const double* sav=sav_all+(size_t)b*SV_STRIDE;
  __shared__ float dmx[NCAD], dmy[NCAD], dmz[NCAD];
  __shared__ float sR[9], sC[Kb];
  __shared__ float s_part[4][17];
  __shared__ double s_yc[96], s_b[3][96], s_dyc[96], s_dyr[96];
  if (tid==0){
    for (int e=0;e<9;e++) sR[e]=(float)sav[SV_R1+18+e];
    for (int k=0;k<Kb;k++) sC[k]=(float)sav[SV_C2+k];
  }
  for (int e=tid;e<96;e+=blockDim.x){
    s_yc[e]=sav[SV_YC+e];
    s_b[0][e]=sav[SV_B1+e];
    s_b[1][e]=sav[SV_B1+96+e];
    s_b[2][e]=sav[SV_B1+192+e];
  }
  for (int j=tid;j<NCAD;j+=blockDim.x){ dmx[j]=0.f; dmy[j]=0.f; dmz[j]=0.f; }
  __syncthreads();
  for (int i=tid;i<Mpc;i+=blockDim.x){
    u64 key=minbuf[(size_t)b*Mpc+i];
    int j=(int)(key&0xffffffffULL);
    float px=pc[((size_t)b*3+0)*Mpc+i], py=pc[((size_t)b*3+1)*Mpc+i], pz=pc[((size_t)b*3+2)*Mpc+i];
    atomicAdd(&dmx[j], model[((size_t)b*3+0)*NCAD+j]-px);
    atomicAdd(&dmy[j], model[((size_t)b*3+1)*NCAD+j]-py);
    atomicAdd(&dmz[j], model[((size_t)b*3+2)*NCAD+j]-pz);
  }
  __syncthreads();
  float vals[17];
  for (int v=0;v<17;v++) vals[v]=0.f;
  for (int j=tid;j<NCAD;j+=blockDim.x){
    float d0=dmx[j], d1=dmy[j], d2v=dmz[j];
    float cv[15];
    for (int k=0;k<Kb;k++) for (int l=0;l<3;l++) cv[k*3+l]=cad[(k*3+l)*NCAD+j];
    float m00=0.f,m01=0.f,m02=0.f;
    for (int k=0;k<Kb;k++){ m00+=sC[k]*cv[k*3+0]; m01+=sC[k]*cv[k*3+1]; m02+=sC[k]*cv[k*3+2]; }
    vals[0]+=d0; vals[1]+=d1; vals[2]+=d2v;
    vals[3]+=d0*m00; vals[4]+=d0*m01; vals[5]+=d0*m02;
    vals[6]+=d1*m00; vals[7]+=d1*m01; vals[8]+=d1*m02;
    vals[9]+=d2v*m00; vals[10]+=d2v*m01; vals[11]+=d2v*m02;
    float t0=sR[0]*d0+sR[3]*d1+sR[6]*d2v;
    float t1=sR[1]*d0+sR[4]*d1+sR[7]*d2v;
    float t2=sR[2]*d0+sR[5]*d1+sR[8]*d2v;
    for (int k=0;k<Kb;k++) vals[12+k]+=t0*cv[k*3+0]+t1*cv[k*3+1]+t2*cv[k*3+2];
  }
  for (int off=32;off>=1;off>>=1)
    for (int v=0;v<17;v++) vals[v]+=__shfl_down(vals[v],off,64);
  int wv=tid>>6, ln=tid&63;
  if (ln==0) for (int v=0;v<17;v++) s_part[wv][v]=vals[v];
  __syncthreads();
  if (tid==0){
    const double* Gi=consts+CD_GI;
    const double* Bmean=consts+CD_BMEAN;
    const double* wd=consts+CD_WD;
    const double* Bc=consts+CD_BC;
    double wsum=consts[CD_WSUM];
    double sc2=2.0/(double)Mpc;
    double red[17];
    for (int v=0;v<17;v++)
      red[v]=((double)s_part[0][v]+(double)s_part[1][v]+(double)s_part[2][v]+(double)s_part[3][v])*sc2;
    double dt[3]={red[0],red[1],red[2]};
    double dRm[3][3];
    for (int i=0;i<3;i++) for (int j=0;j<3;j++) dRm[i][j]=red[3+i*3+j];
    double dc[Kb];
    for (int k=0;k<Kb;k++) dc[k]=red[12+k];
    double c2[Kb];
    for (int k=0;k<Kb;k++) c2[k]=sav[SV_C2+k];
    double R3[3][3];
    for (int e=0;e<9;e++) R3[e/3][e%3]=sav[SV_R1+18+e];
    double bmean[3];
    for (int i=0;i<3;i++){
      double a=0.0;
      for (int k=0;k<Kb;k++) a += c2[k]*Bmean[k*3+i];
      bmean[i]=a;
    }
    // t = ymean - R3*bmean chain
    for (int i=0;i<3;i++) for (int j=0;j<3;j++) dRm[i][j]-=dt[i]*bmean[j];
    double dbm[3];
    for (int i=0;i<3;i++) dbm[i]=-(R3[0][i]*dt[0]+R3[1][i]*dt[1]+R3[2][i]*dt[2]);
    for (int k=0;k<Kb;k++) dc[k]+=dbm[0]*Bmean[k*3+0]+dbm[1]*Bmean[k*3+1]+dbm[2]*Bmean[k*3+2];
    // third procrustes backward
    double dH[3][3];
    proc_bwd(dRm, sav+SV_U1+2*SV_USTR, dH);
    for (int i=0;i<3;i++) for (int n=0;n<Npts;n++)
      s_dyc[i*Npts+n]=wd[n]*(dH[i][0]*s_b[2][n]+dH[i][1]*s_b[2][Npts+n]+dH[i][2]*s_b[2][2*Npts+n]);
    for (int n=0;n<Npts;n++) for (int j=0;j<3;j++){
      double db=wd[n]*(dH[0][j]*s_yc[n]+dH[1][j]*s_yc[Npts+n]+dH[2][j]*s_yc[2*Npts+n]);
      for (int k=0;k<Kb;k++) dc[k]+=db*Bc[(k*3+j)*Npts+n];
    }
    // two shape-LS iterations backward
    for (int it=1; it>=0; --it){
      double dh[Kb];
      for (int k=0;k<Kb;k++){
        double a=0.0;
        for (int l=0;l<Kb;l++) a += Gi[k*Kb+l]*dc[l];
        dh[k]=a;
      }
      for (int i=0;i<3;i++) for (int n=0;n<Npts;n++){
        double a=0.0;
        for (int k=0;k<Kb;k++) a += dh[k]*Bc[(k*3+i)*Npts+n];
        s_dyr[i*Npts+n]=wd[n]*a;
      }
      double dR2[3][3];
      for (int j=0;j<3;j++) for (int i=0;i<3;i++){
        double a=0.0;
        for (int n=0;n<Npts;n++) a += s_yc[j*Npts+n]*s_dyr[i*Npts+n];
        dR2[j][i]=a;
      }
      const double* Rr=sav+SV_R1+it*9;
      for (int j=0;j<3;j++) for (int n=0;n<Npts;n++)
        s_dyc[j*Npts+n]+=Rr[j*3+0]*s_dyr[n]+Rr[j*3+1]*s_dyr[Npts+n]+Rr[j*3+2]*s_dyr[2*Npts+n];
      proc_bwd(dR2, sav+SV_U1+it*SV_USTR, dH);
      for (int i=0;i<3;i++) for (int n=0;n<Npts;n++)
        s_dyc[i*Npts+n]+=wd[n]*(dH[i][0]*s_b[it][n]+dH[i][1]*s_b[it][Npts+n]+dH[i][2]*s_b[it][2*Npts+n]);
      if (it>0){
        for (int k=0;k<Kb;k++) dc[k]=0.0;
        for (int n=0;n<Npts;n++) for (int j=0;j<3;j++){
          double db=wd[n]*(dH[0][j]*s_yc[n]+dH[1][j]*s_yc[Npts+n]+dH[2][j]*s_yc[2*Npts+n]);
          for (int k=0;k<Kb;k++) dc[k]+=db*Bc[(k*3+j)*Npts+n];
        }
      }
    }
    // y = yc + mean chain;  dymean = dt
    for (int i=0;i<3;i++){
      double S=0.0;
      for (int n=0;n<Npts;n++) S+=s_dyc[i*Npts+n];
      for (int n=0;n<Npts;n++){
        double dy=s_dyc[i*Npts+n]+wd[n]/wsum*(dt[i]-S);
        corr[b*96+i*Npts+n]-=(float)(0.5*dy);
      }
    }
  }
}

__global__ void k_final(const float* __restrict__ kp, const float* __restrict__ corr,
                        const double* __restrict__ consts, double* __restrict__ sav,
                        float* __restrict__ out)
{
  int b=blockIdx.x;
  __shared__ double s_yc[96], s_bb[96], s_yr[96];
  if (threadIdx.x==0){
    double R3[3][3], tv[3], c2[Kb];
    pace_forward(kp+b*96, corr+b*96, consts, s_yc, s_bb, s_yr, sav+(size_t)b*SV_STRIDE, R3, tv, c2);
    for (int i=0;i<3;i++) for (int j=0;j<3;j++) out[b*9+i*3+j]=(float)R3[i][j];
    for (int i=0;i<3;i++) out[72+b*3+i]=(float)tv[i];
    for (int k=0;k<Kb;k++) out[96+b*5+k]=(float)c2[k];
    for (int e=0;e<96;e++){
      float cvv=corr[b*96+e];
      out[136+b*96+e]=cvv;
      out[904+b*96+e]=kp[b*96+e]+cvv;
    }
  }
}

extern "C" void kernel_launch(void* const* d_in, const int* in_sizes, int n_in,
                              void* d_out, int out_size, void* d_ws, size_t ws_size,
                              hipStream_t stream) {
  const float* pc   =(const float*)d_in[0];
  const float* kp   =(const float*)d_in[1];
  const float* corr0=(const float*)d_in[2];
  const float* mkp  =(const float*)d_in[3];
  const float* cad  =(const float*)d_in[4];
  const float* w    =(const float*)d_in[5];
  const float* lam  =(const float*)d_in[6];
  float* out=(float*)d_out;
  char* ws=(char*)d_ws;
  float*  corr   =(float*)(ws+0);          // 768 floats
  double* consts =(double*)(ws+4096);      // 560 doubles
  double* sav    =(double*)(ws+12288);     // 8*512 doubles
  float*  model  =(float*)(ws+45056);      // 8*3*2048 floats
  u64*    minbuf =(u64*)(ws+241664);       // 8*4096 u64

  hipLaunchKernelGGL(k_init, dim3(1), dim3(256), 0, stream, corr0, mkp, w, lam, corr, consts);
  for (int s=0; s<NSTEPS; ++s){
    hipLaunchKernelGGL(k_pace_model, dim3(Bsz), dim3(256), 0, stream,
                       kp, cad, corr, consts, sav, model, minbuf);
    hipLaunchKernelGGL(k_chamfer, dim3(Mpc/512, NCAD/512, Bsz), dim3(256), 0, stream,
                       pc, model, minbuf);
    hipLaunchKernelGGL(k_grad, dim3(Bsz), dim3(256), 0, stream,
                       pc, cad, model, minbuf, consts, sav, corr);
  }
  hipLaunchKernelGGL(k_final, dim3(Bsz), dim3(64), 0, stream, kp, corr, consts, sav, out);
}

// Round 3
// 1422.249 us; speedup vs baseline: 3.9059x; 3.9059x over previous
//
#include <hip/hip_runtime.h>

typedef unsigned long long u64;

#define Bsz 8
#define Npts 32
#define Kb 5
#define Mpc 4096
#define NCAD 2048
#define NSTEPS 20

// consts (doubles) layout
#define CD_GI 0      // 25
#define CD_BMEAN 25  // 15
#define CD_WD 40     // 32
#define CD_WSUM 72
#define CD_LAMK 74
#define CD_BC 80     // 480
// sav per-b layout (doubles), stride 512
#define SV_YC 0      // 96
#define SV_B1 96     // 3 x 96
#define SV_R1 384    // 3 x 9
#define SV_U1 411    // 3 x 22 (U9,s3,V9,d1)
#define SV_C2 477    // 5
#define SV_STRIDE 512
#define SV_USTR 22

// ---------- wave-half (32-lane) fp64 butterfly sum; lanes 32..63 mirror 0..31 ----------
__device__ __forceinline__ double wsum32(double v){
  v += __shfl_xor(v, 1, 64);
  v += __shfl_xor(v, 2, 64);
  v += __shfl_xor(v, 4, 64);
  v += __shfl_xor(v, 8, 64);
  v += __shfl_xor(v,16, 64);
  return v;
}

// ---------------- fp64 3x3 helpers (uniform data on all lanes) ----------------
__device__ __forceinline__ double det3d(const double M[3][3]){
  return M[0][0]*(M[1][1]*M[2][2]-M[1][2]*M[2][1])
       - M[0][1]*(M[1][0]*M[2][2]-M[1][2]*M[2][0])
       + M[0][2]*(M[1][0]*M[2][1]-M[1][1]*M[2][0]);
}

#define JROT(p,q,u) { \
  double apq=A[p][q]; \
  if (fabs(apq)>1e-300){ \
    double theta=(A[q][q]-A[p][p])/(2.0*apq); \
    double tt=(theta>=0.0)?1.0/(theta+sqrt(1.0+theta*theta)):1.0/(theta-sqrt(1.0+theta*theta)); \
    double cc=1.0/sqrt(1.0+tt*tt), ssn=tt*cc; \
    double app=A[p][p], aqq=A[q][q]; \
    A[p][p]=app-tt*apq; A[q][q]=aqq+tt*apq; A[p][q]=0.0; A[q][p]=0.0; \
    double aup=A[u][p], auq=A[u][q]; \
    A[u][p]=cc*aup-ssn*auq; A[p][u]=A[u][p]; \
    A[u][q]=ssn*aup+cc*auq; A[q][u]=A[u][q]; \
    for (int i_=0;i_<3;i_++){ double vip=V[i_][p], viq=V[i_][q]; V[i_][p]=cc*vip-ssn*viq; V[i_][q]=ssn*vip+cc*viq; } \
  } }

__device__ void svd3(const double H[3][3], double U[3][3], double s[3], double V[3][3], double* dsg)
{
  double A[3][3];
  for (int i=0;i<3;i++) for (int j=0;j<3;j++){
    double a=0.0;
    for (int k=0;k<3;k++) a += H[k][i]*H[k][j];
    A[i][j]=a;
  }
  V[0][0]=1;V[0][1]=0;V[0][2]=0; V[1][0]=0;V[1][1]=1;V[1][2]=0; V[2][0]=0;V[2][1]=0;V[2][2]=1;
  for (int sweep=0; sweep<8; ++sweep){
    double off=fabs(A[0][1])+fabs(A[0][2])+fabs(A[1][2]);
    double dia=fabs(A[0][0])+fabs(A[1][1])+fabs(A[2][2]);
    if (off <= 1e-14*dia + 1e-300) break;
    JROT(0,1,2)
    JROT(0,2,1)
    JROT(1,2,0)
  }
  double e0=A[0][0], e1=A[1][1], e2=A[2][2];
  if (e0<e1){ double t=e0;e0=e1;e1=t; for(int i=0;i<3;i++){double tv=V[i][0];V[i][0]=V[i][1];V[i][1]=tv;} }
  if (e0<e2){ double t=e0;e0=e2;e2=t; for(int i=0;i<3;i++){double tv=V[i][0];V[i][0]=V[i][2];V[i][2]=tv;} }
  if (e1<e2){ double t=e1;e1=e2;e2=t; for(int i=0;i<3;i++){double tv=V[i][1];V[i][1]=V[i][2];V[i][2]=tv;} }
  for (int c=0;c<3;c++){
    double u0=H[0][0]*V[0][c]+H[0][1]*V[1][c]+H[0][2]*V[2][c];
    double u1=H[1][0]*V[0][c]+H[1][1]*V[1][c]+H[1][2]*V[2][c];
    double u2=H[2][0]*V[0][c]+H[2][1]*V[1][c]+H[2][2]*V[2][c];
    double nr=sqrt(u0*u0+u1*u1+u2*u2);
    s[c]=nr;
    double inv=(nr>1e-300)?1.0/nr:0.0;
    U[0][c]=u0*inv; U[1][c]=u1*inv; U[2][c]=u2*inv;
  }
  if (s[2] <= 1e-12*s[0]){
    U[0][2]=U[1][0]*U[2][1]-U[2][0]*U[1][1];
    U[1][2]=U[2][0]*U[0][1]-U[0][0]*U[2][1];
    U[2][2]=U[0][0]*U[1][1]-U[1][0]*U[0][1];
  }
  double dd=det3d(U)*det3d(V);
  *dsg = (dd>=0.0)?1.0:-1.0;
}

// VJP of R = U diag(1,1,d) V^T
__device__ void proc_bwd(const double dRm[3][3], const double* sv, double dH[3][3])
{
  double U[3][3],V[3][3],s[3],dsg;
  for (int i=0;i<3;i++) for (int j=0;j<3;j++){ U[i][j]=sv[i*3+j]; V[i][j]=sv[12+i*3+j]; }
  s[0]=sv[9]; s[1]=sv[10]; s[2]=sv[11];
  dsg=sv[21];
  double A0[3][3];
  for (int a=0;a<3;a++) for (int c=0;c<3;c++){
    double x=0.0;
    for (int i=0;i<3;i++) for (int j=0;j<3;j++) x += U[i][a]*dRm[i][j]*V[j][c];
    A0[a][c]=x;
  }
  double D[3]={1.0,1.0,dsg};
  double Q[3][3]={{0,0,0},{0,0,0},{0,0,0}};
  for (int i=0;i<3;i++) for (int j=0;j<3;j++){
    if (i==j) continue;
    double Muu=A0[i][j]*D[j]-D[i]*A0[j][i];
    double Mvv=A0[j][i]*D[j]-D[i]*A0[i][j];
    double den=s[j]*s[j]-s[i]*s[i];
    if (fabs(den)<1e-30) den=(den>=0.0?1e-30:-1e-30);
    Q[i][j]=(Muu*s[j]+s[i]*Mvv)/den;
  }
  for (int i=0;i<3;i++) for (int j=0;j<3;j++){
    double x=0.0;
    for (int a=0;a<3;a++) for (int c=0;c<3;c++) x += U[i][a]*Q[a][c]*V[j][c];
    dH[i][j]=x;
  }
}

// ---------------- wave-parallel PACE forward (one wave, lane n = point lane&31) ----------------
__device__ void pace_fwd_wave(const double y[3], const double* consts, double* sav,
                              int lane, int save,
                              double R3[3][3], double tvec[3], double cout[Kb])
{
  int n = lane & 31;
  const double* Gi=consts+CD_GI;
  const double* Bmean=consts+CD_BMEAN;
  double wsum=consts[CD_WSUM], lamK=consts[CD_LAMK];
  double wd_n=consts[CD_WD+n];
  double Bc_n[15];
  for (int e=0;e<15;e++) Bc_n[e]=consts[CD_BC+e*Npts+n];

  double ymean[3], yc[3];
  for (int i=0;i<3;i++) ymean[i]=wsum32(y[i]*wd_n)/wsum;
  for (int i=0;i<3;i++) yc[i]=y[i]-ymean[i];
  if (save && lane<32) for (int i=0;i<3;i++) sav[SV_YC+i*Npts+n]=yc[i];

  double c[Kb];
  for (int k=0;k<Kb;k++) c[k]=1.0/(double)Kb;

  for (int r=0;r<3;r++){
    double bb[3];
    for (int i=0;i<3;i++){
      double a=0.0;
      for (int k=0;k<Kb;k++) a+=c[k]*Bc_n[k*3+i];
      bb[i]=a;
    }
    double H[3][3];
    for (int i=0;i<3;i++){
      double wy=yc[i]*wd_n;
      for (int j=0;j<3;j++) H[i][j]=wsum32(wy*bb[j]);
    }
    double U[3][3],V[3][3],s[3],dsg;
    svd3(H,U,s,V,&dsg);
    double R[3][3];
    for (int i=0;i<3;i++) for (int j=0;j<3;j++)
      R[i][j]=U[i][0]*V[j][0]+U[i][1]*V[j][1]+dsg*U[i][2]*V[j][2];

    if (save){
      if (lane<32) for (int i=0;i<3;i++) sav[SV_B1+r*96+i*Npts+n]=bb[i];
      if (lane==0){
        double* pr=sav+SV_R1+r*9;
        for (int i=0;i<3;i++) for (int j=0;j<3;j++) pr[i*3+j]=R[i][j];
        double* pu=sav+SV_U1+r*SV_USTR;
        for (int i=0;i<3;i++) for (int j=0;j<3;j++){ pu[i*3+j]=U[i][j]; pu[12+i*3+j]=V[i][j]; }
        pu[9]=s[0]; pu[10]=s[1]; pu[11]=s[2]; pu[21]=dsg;
      }
    }

    if (r<2){
      double yr[3];
      for (int i=0;i<3;i++) yr[i]=R[0][i]*yc[0]+R[1][i]*yc[1]+R[2][i]*yc[2];
      double h[Kb];
      for (int k=0;k<Kb;k++){
        double p=(Bc_n[k*3+0]*yr[0]+Bc_n[k*3+1]*yr[1]+Bc_n[k*3+2]*yr[2])*wd_n;
        h[k]=wsum32(p)+lamK;
      }
      for (int k=0;k<Kb;k++){
        double a=0.0;
        for (int l=0;l<Kb;l++) a+=Gi[k*Kb+l]*h[l];
        c[k]=a;
      }
    } else {
      for (int i=0;i<3;i++) for (int j=0;j<3;j++) R3[i][j]=R[i][j];
    }
  }
  double bmean[3];
  for (int i=0;i<3;i++){
    double a=0.0;
    for (int k=0;k<Kb;k++) a+=c[k]*Bmean[k*3+i];
    bmean[i]=a;
  }
  for (int i=0;i<3;i++)
    tvec[i]=ymean[i]-(R3[i][0]*bmean[0]+R3[i][1]*bmean[1]+R3[i][2]*bmean[2]);
  for (int k=0;k<Kb;k++) cout[k]=c[k];
  if (save && lane==0) for (int k=0;k<Kb;k++) sav[SV_C2+k]=c[k];
}

// ---------------- wave-parallel PACE backward ----------------
__device__ void pace_bwd_wave(const double red[17], const double* consts, const double* sav,
                              int lane, double dy[3])
{
  int n = lane & 31;
  const double* Gi=consts+CD_GI;
  const double* Bmean=consts+CD_BMEAN;
  double wsum=consts[CD_WSUM];
  double wd_n=consts[CD_WD+n];
  double Bc_n[15];
  for (int e=0;e<15;e++) Bc_n[e]=consts[CD_BC+e*Npts+n];
  double yc[3], b0v[3], b1v[3], b2v[3];
  for (int i=0;i<3;i++){
    yc[i] =sav[SV_YC+i*Npts+n];
    b0v[i]=sav[SV_B1+0*96+i*Npts+n];
    b1v[i]=sav[SV_B1+1*96+i*Npts+n];
    b2v[i]=sav[SV_B1+2*96+i*Npts+n];
  }
  double c2[Kb];
  for (int k=0;k<Kb;k++) c2[k]=sav[SV_C2+k];
  double R3[3][3];
  for (int i=0;i<3;i++) for (int j=0;j<3;j++) R3[i][j]=sav[SV_R1+18+i*3+j];

  double dt[3]={red[0],red[1],red[2]};
  double dRm[3][3];
  for (int i=0;i<3;i++) for (int j=0;j<3;j++) dRm[i][j]=red[3+i*3+j];
  double dc[Kb];
  for (int k=0;k<Kb;k++) dc[k]=red[12+k];

  double bmean[3];
  for (int i=0;i<3;i++){ double a=0.0; for (int k=0;k<Kb;k++) a+=c2[k]*Bmean[k*3+i]; bmean[i]=a; }
  for (int i=0;i<3;i++) for (int j=0;j<3;j++) dRm[i][j]-=dt[i]*bmean[j];
  double dbm[3];
  for (int i=0;i<3;i++) dbm[i]=-(R3[0][i]*dt[0]+R3[1][i]*dt[1]+R3[2][i]*dt[2]);
  for (int k=0;k<Kb;k++) dc[k]+=dbm[0]*Bmean[k*3+0]+dbm[1]*Bmean[k*3+1]+dbm[2]*Bmean[k*3+2];

  double dH[3][3];
  proc_bwd(dRm, sav+SV_U1+2*SV_USTR, dH);
  double dyc[3];
  for (int i=0;i<3;i++)
    dyc[i]=wd_n*(dH[i][0]*b2v[0]+dH[i][1]*b2v[1]+dH[i][2]*b2v[2]);
  {
    double dcp[Kb]={0,0,0,0,0};
    for (int j=0;j<3;j++){
      double db=wd_n*(dH[0][j]*yc[0]+dH[1][j]*yc[1]+dH[2][j]*yc[2]);
      for (int k=0;k<Kb;k++) dcp[k]+=db*Bc_n[k*3+j];
    }
    for (int k=0;k<Kb;k++) dc[k]+=wsum32(dcp[k]);
  }
  #pragma unroll
  for (int it=1; it>=0; --it){
    double dh[Kb];
    for (int k=0;k<Kb;k++){ double a=0.0; for (int l=0;l<Kb;l++) a+=Gi[k*Kb+l]*dc[l]; dh[k]=a; }
    double dyr[3];
    for (int i=0;i<3;i++){
      double a=0.0;
      for (int k=0;k<Kb;k++) a+=dh[k]*Bc_n[k*3+i];
      dyr[i]=wd_n*a;
    }
    double dR2[3][3];
    for (int j=0;j<3;j++) for (int i=0;i<3;i++) dR2[j][i]=wsum32(yc[j]*dyr[i]);
    double Rr[9];
    for (int e=0;e<9;e++) Rr[e]=sav[SV_R1+it*9+e];
    for (int j=0;j<3;j++) dyc[j]+=Rr[j*3+0]*dyr[0]+Rr[j*3+1]*dyr[1]+Rr[j*3+2]*dyr[2];
    proc_bwd(dR2, sav+SV_U1+it*SV_USTR, dH);
    double bs0,bs1,bs2;
    if (it==1){ bs0=b1v[0]; bs1=b1v[1]; bs2=b1v[2]; }
    else      { bs0=b0v[0]; bs1=b0v[1]; bs2=b0v[2]; }
    for (int i=0;i<3;i++) dyc[i]+=wd_n*(dH[i][0]*bs0+dH[i][1]*bs1+dH[i][2]*bs2);
    if (it>0){
      double dcp[Kb]={0,0,0,0,0};
      for (int j=0;j<3;j++){
        double db=wd_n*(dH[0][j]*yc[0]+dH[1][j]*yc[1]+dH[2][j]*yc[2]);
        for (int k=0;k<Kb;k++) dcp[k]+=db*Bc_n[k*3+j];
      }
      for (int k=0;k<Kb;k++) dc[k]=wsum32(dcp[k]);
    }
  }
  for (int i=0;i<3;i++){
    double S=wsum32(dyc[i]);
    dy[i]=dyc[i]+wd_n/wsum*(dt[i]-S);
  }
}

// ---------------- kernels ----------------
__global__ void k_setup(const float* __restrict__ corr0, const float* __restrict__ mkp,
                        const float* __restrict__ w, const float* __restrict__ lamp,
                        float* __restrict__ corr, double* __restrict__ consts)
{
  int lane=threadIdx.x;       // 64 threads
  int n=lane&31;
  for (int e=lane;e<Bsz*96;e+=64) corr[e]=corr0[e];
  double wv=(double)w[n];
  double wsum=wsum32(wv);
  double mk[15];
  for (int e=0;e<15;e++) mk[e]=(double)mkp[e*Npts+n];
  double Bm[15];
  for (int e=0;e<15;e++) Bm[e]=wsum32(mk[e]*wv)/wsum;
  double Bc_n[15];
  for (int e=0;e<15;e++) Bc_n[e]=mk[e]-Bm[e];
  double lam=(double)lamp[0];
  double G[Kb][Kb];
  for (int k=0;k<Kb;k++) for (int l=0;l<Kb;l++){
    double p=(Bc_n[k*3+0]*Bc_n[l*3+0]+Bc_n[k*3+1]*Bc_n[l*3+1]+Bc_n[k*3+2]*Bc_n[l*3+2])*wv;
    G[k][l]=wsum32(p)+((k==l)?lam:0.0);
  }
  // Gauss-Jordan inverse (redundant on all lanes; uniform data)
  double Aug[Kb][2*Kb];
  for (int i=0;i<Kb;i++) for (int j=0;j<Kb;j++){ Aug[i][j]=G[i][j]; Aug[i][Kb+j]=(i==j)?1.0:0.0; }
  for (int col=0;col<Kb;col++){
    int piv=col; double best=fabs(Aug[col][col]);
    for (int r=col+1;r<Kb;r++) if (fabs(Aug[r][col])>best){best=fabs(Aug[r][col]);piv=r;}
    if (piv!=col) for (int j=0;j<2*Kb;j++){ double t=Aug[col][j]; Aug[col][j]=Aug[piv][j]; Aug[piv][j]=t; }
    double ip=1.0/Aug[col][col];
    for (int j=0;j<2*Kb;j++) Aug[col][j]*=ip;
    for (int r=0;r<Kb;r++) if (r!=col){
      double f=Aug[r][col];
      for (int j=0;j<2*Kb;j++) Aug[r][j]-=f*Aug[col][j];
    }
  }
  if (lane<32){
    consts[CD_WD+n]=wv;
    for (int e=0;e<15;e++) consts[CD_BC+e*Npts+n]=Bc_n[e];
  }
  if (lane==0){
    consts[CD_WSUM]=wsum;
    consts[CD_LAMK]=lam/(double)Kb;
    for (int e=0;e<15;e++) consts[CD_BMEAN+e]=Bm[e];
    for (int k=0;k<Kb;k++) for (int l=0;l<Kb;l++) consts[CD_GI+k*Kb+l]=Aug[k][Kb+l];
  }
}

__global__ __launch_bounds__(256,1) void k_pace(const float* __restrict__ kp, const float* __restrict__ cad,
                      const float* __restrict__ corr, const double* __restrict__ consts,
                      double* __restrict__ sav_all, float* __restrict__ model,
                      u64* __restrict__ minbuf)
{
  int b=blockIdx.x, tid=threadIdx.x;
  __shared__ float sR[9], sT[3], sC[Kb];
  if (tid<64){
    int lane=tid, n=lane&31;
    double y[3];
    for (int i=0;i<3;i++)
      y[i]=(double)kp[b*96+i*Npts+n]+(double)corr[b*96+i*Npts+n];
    double R3[3][3],tv[3],cc[Kb];
    pace_fwd_wave(y,consts,sav_all+(size_t)b*SV_STRIDE,lane,1,R3,tv,cc);
    if (lane==0){
      for (int i=0;i<3;i++){ sT[i]=(float)tv[i]; for (int j=0;j<3;j++) sR[i*3+j]=(float)R3[i][j]; }
      for (int k=0;k<Kb;k++) sC[k]=(float)cc[k];
    }
  }
  __syncthreads();
  for (int j=tid;j<NCAD;j+=256){
    float m0=0.f,m1=0.f,m2=0.f;
    for (int k=0;k<Kb;k++){
      m0+=sC[k]*cad[(k*3+0)*NCAD+j];
      m1+=sC[k]*cad[(k*3+1)*NCAD+j];
      m2+=sC[k]*cad[(k*3+2)*NCAD+j];
    }
    model[(b*3+0)*NCAD+j]=sR[0]*m0+sR[1]*m1+sR[2]*m2+sT[0];
    model[(b*3+1)*NCAD+j]=sR[3]*m0+sR[4]*m1+sR[5]*m2+sT[1];
    model[(b*3+2)*NCAD+j]=sR[6]*m0+sR[7]*m1+sR[8]*m2+sT[2];
  }
  for (int i=tid;i<Mpc;i+=256) minbuf[b*Mpc+i]=~0ull;
}

__global__ void k_chamfer(const float* __restrict__ pc, const float* __restrict__ model,
                          u64* __restrict__ minbuf)
{
  int b=blockIdx.z;
  int jbase=blockIdx.y*256;
  int ibase=blockIdx.x*512;
  int t=threadIdx.x;
  __shared__ float mx[256],my[256],mz[256];
  mx[t]=model[(b*3+0)*NCAD+jbase+t];
  my[t]=model[(b*3+1)*NCAD+jbase+t];
  mz[t]=model[(b*3+2)*NCAD+jbase+t];
  __syncthreads();
  int i0=ibase+t, i1=i0+256;
  float x0=pc[(b*3+0)*Mpc+i0], y0=pc[(b*3+1)*Mpc+i0], z0=pc[(b*3+2)*Mpc+i0];
  float x1=pc[(b*3+0)*Mpc+i1], y1=pc[(b*3+1)*Mpc+i1], z1=pc[(b*3+2)*Mpc+i1];
  float d0b=3.4e38f, d1b=3.4e38f;
  int j0=0, j1=0;
  #pragma unroll 4
  for (int j=0;j<256;j++){
    float ax=mx[j], ay=my[j], az=mz[j];
    float dx=x0-ax, dy=y0-ay, dz=z0-az;
    float d2=dx*dx+dy*dy+dz*dz;
    if (d2<d0b){d0b=d2;j0=j;}
    dx=x1-ax; dy=y1-ay; dz=z1-az;
    d2=dx*dx+dy*dy+dz*dz;
    if (d2<d1b){d1b=d2;j1=j;}
  }
  atomicMin(&minbuf[b*Mpc+i0], ((u64)__float_as_uint(d0b)<<32)|(u64)(unsigned)(jbase+j0));
  atomicMin(&minbuf[b*Mpc+i1], ((u64)__float_as_uint(d1b)<<32)|(u64)(unsigned)(jbase+j1));
}

__global__ __launch_bounds__(256,1) void k_update(const float* __restrict__ pc, const float* __restrict__ kp,
                        const float* __restrict__ cad, float* __restrict__ model,
                        u64* __restrict__ minbuf, const double* __restrict__ consts,
                        double* __restrict__ sav_all, float* __restrict__ corr,
                        float* __restrict__ out, int last)
{
  int b=blockIdx.x, tid=threadIdx.x;
  double* sav=sav_all+(size_t)b*SV_STRIDE;
  __shared__ float dmx[NCAD], dmy[NCAD], dmz[NCAD];
  __shared__ float s_part[4][17];
  __shared__ float sR[9], sT[3], sC[Kb];

  for (int j=tid;j<NCAD;j+=256){ dmx[j]=0.f; dmy[j]=0.f; dmz[j]=0.f; }
  __syncthreads();
  for (int i=tid;i<Mpc;i+=256){
    u64 key=minbuf[b*Mpc+i];
    int j=(int)(key&0xffffffffULL);
    float px=pc[(b*3+0)*Mpc+i], py=pc[(b*3+1)*Mpc+i], pz=pc[(b*3+2)*Mpc+i];
    atomicAdd(&dmx[j], model[(b*3+0)*NCAD+j]-px);
    atomicAdd(&dmy[j], model[(b*3+1)*NCAD+j]-py);
    atomicAdd(&dmz[j], model[(b*3+2)*NCAD+j]-pz);
  }
  __syncthreads();

  float cR[9], cC[Kb];
  for (int e=0;e<9;e++) cR[e]=(float)sav[SV_R1+18+e];
  for (int k=0;k<Kb;k++) cC[k]=(float)sav[SV_C2+k];
  float vals[17];
  for (int v=0;v<17;v++) vals[v]=0.f;
  for (int j=tid;j<NCAD;j+=256){
    float d0=dmx[j], d1=dmy[j], d2v=dmz[j];
    float cv[15];
    for (int e=0;e<15;e++) cv[e]=cad[e*NCAD+j];
    float m00=0.f,m01=0.f,m02=0.f;
    for (int k=0;k<Kb;k++){ m00+=cC[k]*cv[k*3+0]; m01+=cC[k]*cv[k*3+1]; m02+=cC[k]*cv[k*3+2]; }
    vals[0]+=d0; vals[1]+=d1; vals[2]+=d2v;
    vals[3]+=d0*m00; vals[4]+=d0*m01; vals[5]+=d0*m02;
    vals[6]+=d1*m00; vals[7]+=d1*m01; vals[8]+=d1*m02;
    vals[9]+=d2v*m00; vals[10]+=d2v*m01; vals[11]+=d2v*m02;
    float t0=cR[0]*d0+cR[3]*d1+cR[6]*d2v;
    float t1=cR[1]*d0+cR[4]*d1+cR[7]*d2v;
    float t2=cR[2]*d0+cR[5]*d1+cR[8]*d2v;
    for (int k=0;k<Kb;k++) vals[12+k]+=t0*cv[k*3+0]+t1*cv[k*3+1]+t2*cv[k*3+2];
  }
  for (int m=1;m<64;m<<=1)
    for (int v=0;v<17;v++) vals[v]+=__shfl_xor(vals[v],m,64);
  int wv=tid>>6;
  if ((tid&63)==0) for (int v=0;v<17;v++) s_part[wv][v]=vals[v];
  __syncthreads();

  if (tid<64){
    int lane=tid, n=lane&31;
    double red[17];
    for (int v=0;v<17;v++)
      red[v]=((double)s_part[0][v]+(double)s_part[1][v]+(double)s_part[2][v]+(double)s_part[3][v])*(2.0/(double)Mpc);
    double dy[3];
    pace_bwd_wave(red,consts,sav,lane,dy);
    float newc[3];
    for (int i=0;i<3;i++){
      double oc=(double)corr[b*96+i*Npts+n];
      newc[i]=(float)(oc-0.5*dy[i]);
      if (lane<32) corr[b*96+i*Npts+n]=newc[i];
    }
    double y[3];
    for (int i=0;i<3;i++) y[i]=(double)kp[b*96+i*Npts+n]+(double)newc[i];
    double R3[3][3],tv[3],cc[Kb];
    pace_fwd_wave(y,consts,sav,lane,last?0:1,R3,tv,cc);
    if (!last){
      if (lane==0){
        for (int i=0;i<3;i++){ sT[i]=(float)tv[i]; for (int j=0;j<3;j++) sR[i*3+j]=(float)R3[i][j]; }
        for (int k=0;k<Kb;k++) sC[k]=(float)cc[k];
      }
    } else {
      if (lane==0){
        for (int i=0;i<3;i++) for (int j=0;j<3;j++) out[b*9+i*3+j]=(float)R3[i][j];
        for (int i=0;i<3;i++) out[72+b*3+i]=(float)tv[i];
        for (int k=0;k<Kb;k++) out[96+b*Kb+k]=(float)cc[k];
      }
      if (lane<32){
        for (int i=0;i<3;i++){
          out[136+b*96+i*Npts+n]=newc[i];
          out[904+b*96+i*Npts+n]=kp[b*96+i*Npts+n]+newc[i];
        }
      }
    }
  }
  if (!last){
    __syncthreads();
    for (int j=tid;j<NCAD;j+=256){
      float m0=0.f,m1=0.f,m2=0.f;
      for (int k=0;k<Kb;k++){
        m0+=sC[k]*cad[(k*3+0)*NCAD+j];
        m1+=sC[k]*cad[(k*3+1)*NCAD+j];
        m2+=sC[k]*cad[(k*3+2)*NCAD+j];
      }
      model[(b*3+0)*NCAD+j]=sR[0]*m0+sR[1]*m1+sR[2]*m2+sT[0];
      model[(b*3+1)*NCAD+j]=sR[3]*m0+sR[4]*m1+sR[5]*m2+sT[1];
      model[(b*3+2)*NCAD+j]=sR[6]*m0+sR[7]*m1+sR[8]*m2+sT[2];
    }
    for (int i=tid;i<Mpc;i+=256) minbuf[b*Mpc+i]=~0ull;
  }
}

extern "C" void kernel_launch(void* const* d_in, const int* in_sizes, int n_in,
                              void* d_out, int out_size, void* d_ws, size_t ws_size,
                              hipStream_t stream) {
  const float* pc   =(const float*)d_in[0];
  const float* kp   =(const float*)d_in[1];
  const float* corr0=(const float*)d_in[2];
  const float* mkp  =(const float*)d_in[3];
  const float* cad  =(const float*)d_in[4];
  const float* w    =(const float*)d_in[5];
  const float* lam  =(const float*)d_in[6];
  float* out=(float*)d_out;
  char* ws=(char*)d_ws;
  float*  corr   =(float*)(ws+0);          // 768 floats
  double* consts =(double*)(ws+4096);      // 560 doubles
  double* sav    =(double*)(ws+12288);     // 8*512 doubles
  float*  model  =(float*)(ws+45056);      // 8*3*2048 floats
  u64*    minbuf =(u64*)(ws+241664);       // 8*4096 u64

  hipLaunchKernelGGL(k_setup, dim3(1), dim3(64), 0, stream, corr0, mkp, w, lam, corr, consts);
  hipLaunchKernelGGL(k_pace, dim3(Bsz), dim3(256), 0, stream,
                     kp, cad, corr, consts, sav, model, minbuf);
  for (int s=0; s<NSTEPS; ++s){
    hipLaunchKernelGGL(k_chamfer, dim3(8,8,8), dim3(256), 0, stream, pc, model, minbuf);
    hipLaunchKernelGGL(k_update, dim3(Bsz), dim3(256), 0, stream,
                       pc, kp, cad, model, minbuf, consts, sav, corr, out, (s==NSTEPS-1)?1:0);
  }
}

// Round 5
// 1228.781 us; speedup vs baseline: 4.5209x; 1.1574x over previous
//
#include <hip/hip_runtime.h>

typedef unsigned long long u64;

#define Bsz 8
#define Npts 32
#define Kb 5
#define Mpc 4096
#define NCAD 2048
#define NSTEPS 20

// consts (floats) layout
#define CD_GI 0      // 25
#define CD_BMEAN 25  // 15
#define CD_WD 40     // 32
#define CD_WSUM 72
#define CD_LAMK 74
#define CD_BC 80     // 480
// sav per-b layout (floats), stride 512
#define SV_YC 0      // 96
#define SV_B1 96     // 3 x 96
#define SV_R1 384    // 3 x 9
#define SV_U1 411    // 3 x 22 (U9,s3,V9,d1)
#define SV_C2 477    // 5
#define SV_STRIDE 512
#define SV_USTR 22

// ---------- wave-half (32-lane) butterfly sum; lanes 32..63 mirror 0..31 ----------
__device__ __forceinline__ float wsum32(float v){
  v += __shfl_xor(v, 1, 64);
  v += __shfl_xor(v, 2, 64);
  v += __shfl_xor(v, 4, 64);
  v += __shfl_xor(v, 8, 64);
  v += __shfl_xor(v,16, 64);
  return v;
}

// ---------------- fp32 3x3 helpers (uniform data on all lanes) ----------------
__device__ __forceinline__ float det3f(const float M[3][3]){
  return M[0][0]*(M[1][1]*M[2][2]-M[1][2]*M[2][1])
       - M[0][1]*(M[1][0]*M[2][2]-M[1][2]*M[2][0])
       + M[0][2]*(M[1][0]*M[2][1]-M[1][1]*M[2][0]);
}

#define JROTF(p,q,u) { \
  float apq=A[p][q]; \
  if (fabsf(apq)>1e-30f){ \
    float theta=(A[q][q]-A[p][p])/(2.0f*apq); \
    float tt=(theta>=0.0f)?1.0f/(theta+sqrtf(1.0f+theta*theta)):1.0f/(theta-sqrtf(1.0f+theta*theta)); \
    float cc=1.0f/sqrtf(1.0f+tt*tt), ssn=tt*cc; \
    float app=A[p][p], aqq=A[q][q]; \
    A[p][p]=app-tt*apq; A[q][q]=aqq+tt*apq; A[p][q]=0.0f; A[q][p]=0.0f; \
    float aup=A[u][p], auq=A[u][q]; \
    A[u][p]=cc*aup-ssn*auq; A[p][u]=A[u][p]; \
    A[u][q]=ssn*aup+cc*auq; A[q][u]=A[u][q]; \
    for (int i_=0;i_<3;i_++){ float vip=V[i_][p], viq=V[i_][q]; V[i_][p]=cc*vip-ssn*viq; V[i_][q]=ssn*vip+cc*viq; } \
  } }

__device__ void svd3f(const float H[3][3], float U[3][3], float s[3], float V[3][3], float* dsg)
{
  float A[3][3];
  for (int i=0;i<3;i++) for (int j=0;j<3;j++){
    float a=0.0f;
    for (int k=0;k<3;k++) a += H[k][i]*H[k][j];
    A[i][j]=a;
  }
  V[0][0]=1;V[0][1]=0;V[0][2]=0; V[1][0]=0;V[1][1]=1;V[1][2]=0; V[2][0]=0;V[2][1]=0;V[2][2]=1;
  for (int sweep=0; sweep<6; ++sweep){
    float off=fabsf(A[0][1])+fabsf(A[0][2])+fabsf(A[1][2]);
    float dia=fabsf(A[0][0])+fabsf(A[1][1])+fabsf(A[2][2]);
    if (off <= 3e-7f*dia + 1e-30f) break;
    JROTF(0,1,2)
    JROTF(0,2,1)
    JROTF(1,2,0)
  }
  float e0=A[0][0], e1=A[1][1], e2=A[2][2];
  if (e0<e1){ float t=e0;e0=e1;e1=t; for(int i=0;i<3;i++){float tv=V[i][0];V[i][0]=V[i][1];V[i][1]=tv;} }
  if (e0<e2){ float t=e0;e0=e2;e2=t; for(int i=0;i<3;i++){float tv=V[i][0];V[i][0]=V[i][2];V[i][2]=tv;} }
  if (e1<e2){ float t=e1;e1=e2;e2=t; for(int i=0;i<3;i++){float tv=V[i][1];V[i][1]=V[i][2];V[i][2]=tv;} }
  for (int c=0;c<3;c++){
    float u0=H[0][0]*V[0][c]+H[0][1]*V[1][c]+H[0][2]*V[2][c];
    float u1=H[1][0]*V[0][c]+H[1][1]*V[1][c]+H[1][2]*V[2][c];
    float u2=H[2][0]*V[0][c]+H[2][1]*V[1][c]+H[2][2]*V[2][c];
    float nr=sqrtf(u0*u0+u1*u1+u2*u2);
    s[c]=nr;
    float inv=(nr>1e-30f)?1.0f/nr:0.0f;
    U[0][c]=u0*inv; U[1][c]=u1*inv; U[2][c]=u2*inv;
  }
  if (s[2] <= 1e-6f*s[0]){
    U[0][2]=U[1][0]*U[2][1]-U[2][0]*U[1][1];
    U[1][2]=U[2][0]*U[0][1]-U[0][0]*U[2][1];
    U[2][2]=U[0][0]*U[1][1]-U[1][0]*U[0][1];
  }
  float dd=det3f(U)*det3f(V);
  *dsg = (dd>=0.0f)?1.0f:-1.0f;
}

// VJP of R = U diag(1,1,d) V^T
__device__ void proc_bwd(const float dRm[3][3], const float* sv, float dH[3][3])
{
  float U[3][3],V[3][3],s[3],dsg;
  for (int i=0;i<3;i++) for (int j=0;j<3;j++){ U[i][j]=sv[i*3+j]; V[i][j]=sv[12+i*3+j]; }
  s[0]=sv[9]; s[1]=sv[10]; s[2]=sv[11];
  dsg=sv[21];
  float A0[3][3];
  for (int a=0;a<3;a++) for (int c=0;c<3;c++){
    float x=0.0f;
    for (int i=0;i<3;i++) for (int j=0;j<3;j++) x += U[i][a]*dRm[i][j]*V[j][c];
    A0[a][c]=x;
  }
  float D[3]={1.0f,1.0f,dsg};
  float Q[3][3]={{0,0,0},{0,0,0},{0,0,0}};
  for (int i=0;i<3;i++) for (int j=0;j<3;j++){
    if (i==j) continue;
    float Muu=A0[i][j]*D[j]-D[i]*A0[j][i];
    float Mvv=A0[j][i]*D[j]-D[i]*A0[i][j];
    float den=s[j]*s[j]-s[i]*s[i];
    if (fabsf(den)<1e-18f) den=(den>=0.0f?1e-18f:-1e-18f);
    Q[i][j]=(Muu*s[j]+s[i]*Mvv)/den;
  }
  for (int i=0;i<3;i++) for (int j=0;j<3;j++){
    float x=0.0f;
    for (int a=0;a<3;a++) for (int c=0;c<3;c++) x += U[i][a]*Q[a][c]*V[j][c];
    dH[i][j]=x;
  }
}

// ---------------- wave-parallel PACE forward (one wave, lane n = point lane&31) ----------------
__device__ void pace_fwd_wave(const float y[3], const float* consts, float* sav,
                              int lane, int save,
                              float R3[3][3], float tvec[3], float cout[Kb])
{
  int n = lane & 31;
  const float* Gi=consts+CD_GI;
  const float* Bmean=consts+CD_BMEAN;
  float wsum=consts[CD_WSUM], lamK=consts[CD_LAMK];
  float wd_n=consts[CD_WD+n];
  float Bc_n[15];
  for (int e=0;e<15;e++) Bc_n[e]=consts[CD_BC+e*Npts+n];

  float ymean[3], yc[3];
  for (int i=0;i<3;i++) ymean[i]=wsum32(y[i]*wd_n)/wsum;
  for (int i=0;i<3;i++) yc[i]=y[i]-ymean[i];
  if (save && lane<32) for (int i=0;i<3;i++) sav[SV_YC+i*Npts+n]=yc[i];

  float c[Kb];
  for (int k=0;k<Kb;k++) c[k]=1.0f/(float)Kb;

  for (int r=0;r<3;r++){
    float bb[3];
    for (int i=0;i<3;i++){
      float a=0.0f;
      for (int k=0;k<Kb;k++) a+=c[k]*Bc_n[k*3+i];
      bb[i]=a;
    }
    float H[3][3];
    for (int i=0;i<3;i++){
      float wy=yc[i]*wd_n;
      for (int j=0;j<3;j++) H[i][j]=wsum32(wy*bb[j]);
    }
    float U[3][3],V[3][3],s[3],dsg;
    svd3f(H,U,s,V,&dsg);
    float R[3][3];
    for (int i=0;i<3;i++) for (int j=0;j<3;j++)
      R[i][j]=U[i][0]*V[j][0]+U[i][1]*V[j][1]+dsg*U[i][2]*V[j][2];

    if (save){
      if (lane<32) for (int i=0;i<3;i++) sav[SV_B1+r*96+i*Npts+n]=bb[i];
      if (lane==0){
        float* pr=sav+SV_R1+r*9;
        for (int i=0;i<3;i++) for (int j=0;j<3;j++) pr[i*3+j]=R[i][j];
        float* pu=sav+SV_U1+r*SV_USTR;
        for (int i=0;i<3;i++) for (int j=0;j<3;j++){ pu[i*3+j]=U[i][j]; pu[12+i*3+j]=V[i][j]; }
        pu[9]=s[0]; pu[10]=s[1]; pu[11]=s[2]; pu[21]=dsg;
      }
    }

    if (r<2){
      float yr[3];
      for (int i=0;i<3;i++) yr[i]=R[0][i]*yc[0]+R[1][i]*yc[1]+R[2][i]*yc[2];
      float h[Kb];
      for (int k=0;k<Kb;k++){
        float p=(Bc_n[k*3+0]*yr[0]+Bc_n[k*3+1]*yr[1]+Bc_n[k*3+2]*yr[2])*wd_n;
        h[k]=wsum32(p)+lamK;
      }
      for (int k=0;k<Kb;k++){
        float a=0.0f;
        for (int l=0;l<Kb;l++) a+=Gi[k*Kb+l]*h[l];
        c[k]=a;
      }
    } else {
      for (int i=0;i<3;i++) for (int j=0;j<3;j++) R3[i][j]=R[i][j];
    }
  }
  float bmean[3];
  for (int i=0;i<3;i++){
    float a=0.0f;
    for (int k=0;k<Kb;k++) a+=c[k]*Bmean[k*3+i];
    bmean[i]=a;
  }
  for (int i=0;i<3;i++)
    tvec[i]=ymean[i]-(R3[i][0]*bmean[0]+R3[i][1]*bmean[1]+R3[i][2]*bmean[2]);
  for (int k=0;k<Kb;k++) cout[k]=c[k];
  if (save && lane==0) for (int k=0;k<Kb;k++) sav[SV_C2+k]=c[k];
}

// ---------------- wave-parallel PACE backward ----------------
__device__ void pace_bwd_wave(const float red[17], const float* consts, const float* sav,
                              int lane, float dy[3])
{
  int n = lane & 31;
  const float* Gi=consts+CD_GI;
  const float* Bmean=consts+CD_BMEAN;
  float wsum=consts[CD_WSUM];
  float wd_n=consts[CD_WD+n];
  float Bc_n[15];
  for (int e=0;e<15;e++) Bc_n[e]=consts[CD_BC+e*Npts+n];
  float yc[3], b0v[3], b1v[3], b2v[3];
  for (int i=0;i<3;i++){
    yc[i] =sav[SV_YC+i*Npts+n];
    b0v[i]=sav[SV_B1+0*96+i*Npts+n];
    b1v[i]=sav[SV_B1+1*96+i*Npts+n];
    b2v[i]=sav[SV_B1+2*96+i*Npts+n];
  }
  float c2[Kb];
  for (int k=0;k<Kb;k++) c2[k]=sav[SV_C2+k];
  float R3[3][3];
  for (int i=0;i<3;i++) for (int j=0;j<3;j++) R3[i][j]=sav[SV_R1+18+i*3+j];

  float dt[3]={red[0],red[1],red[2]};
  float dRm[3][3];
  for (int i=0;i<3;i++) for (int j=0;j<3;j++) dRm[i][j]=red[3+i*3+j];
  float dc[Kb];
  for (int k=0;k<Kb;k++) dc[k]=red[12+k];

  float bmean[3];
  for (int i=0;i<3;i++){ float a=0.0f; for (int k=0;k<Kb;k++) a+=c2[k]*Bmean[k*3+i]; bmean[i]=a; }
  for (int i=0;i<3;i++) for (int j=0;j<3;j++) dRm[i][j]-=dt[i]*bmean[j];
  float dbm[3];
  for (int i=0;i<3;i++) dbm[i]=-(R3[0][i]*dt[0]+R3[1][i]*dt[1]+R3[2][i]*dt[2]);
  for (int k=0;k<Kb;k++) dc[k]+=dbm[0]*Bmean[k*3+0]+dbm[1]*Bmean[k*3+1]+dbm[2]*Bmean[k*3+2];

  float dH[3][3];
  proc_bwd(dRm, sav+SV_U1+2*SV_USTR, dH);
  float dyc[3];
  for (int i=0;i<3;i++)
    dyc[i]=wd_n*(dH[i][0]*b2v[0]+dH[i][1]*b2v[1]+dH[i][2]*b2v[2]);
  {
    float dcp[Kb]={0,0,0,0,0};
    for (int j=0;j<3;j++){
      float db=wd_n*(dH[0][j]*yc[0]+dH[1][j]*yc[1]+dH[2][j]*yc[2]);
      for (int k=0;k<Kb;k++) dcp[k]+=db*Bc_n[k*3+j];
    }
    for (int k=0;k<Kb;k++) dc[k]+=wsum32(dcp[k]);
  }
  #pragma unroll
  for (int it=1; it>=0; --it){
    float dh[Kb];
    for (int k=0;k<Kb;k++){ float a=0.0f; for (int l=0;l<Kb;l++) a+=Gi[k*Kb+l]*dc[l]; dh[k]=a; }
    float dyr[3];
    for (int i=0;i<3;i++){
      float a=0.0f;
      for (int k=0;k<Kb;k++) a+=dh[k]*Bc_n[k*3+i];
      dyr[i]=wd_n*a;
    }
    float dR2[3][3];
    for (int j=0;j<3;j++) for (int i=0;i<3;i++) dR2[j][i]=wsum32(yc[j]*dyr[i]);
    float Rr[9];
    for (int e=0;e<9;e++) Rr[e]=sav[SV_R1+it*9+e];
    for (int j=0;j<3;j++) dyc[j]+=Rr[j*3+0]*dyr[0]+Rr[j*3+1]*dyr[1]+Rr[j*3+2]*dyr[2];
    proc_bwd(dR2, sav+SV_U1+it*SV_USTR, dH);
    float bs0,bs1,bs2;
    if (it==1){ bs0=b1v[0]; bs1=b1v[1]; bs2=b1v[2]; }
    else      { bs0=b0v[0]; bs1=b0v[1]; bs2=b0v[2]; }
    for (int i=0;i<3;i++) dyc[i]+=wd_n*(dH[i][0]*bs0+dH[i][1]*bs1+dH[i][2]*bs2);
    if (it>0){
      float dcp[Kb]={0,0,0,0,0};
      for (int j=0;j<3;j++){
        float db=wd_n*(dH[0][j]*yc[0]+dH[1][j]*yc[1]+dH[2][j]*yc[2]);
        for (int k=0;k<Kb;k++) dcp[k]+=db*Bc_n[k*3+j];
      }
      for (int k=0;k<Kb;k++) dc[k]=wsum32(dcp[k]);
    }
  }
  for (int i=0;i<3;i++){
    float S=wsum32(dyc[i]);
    dy[i]=dyc[i]+wd_n/wsum*(dt[i]-S);
  }
}

// ---------------- kernels ----------------
// one-time setup in fp64 (cost irrelevant), stores fp32 consts
__global__ void k_setup(const float* __restrict__ corr0, const float* __restrict__ mkp,
                        const float* __restrict__ w, const float* __restrict__ lamp,
                        float* __restrict__ corr, float* __restrict__ consts)
{
  int lane=threadIdx.x;       // 64 threads
  int n=lane&31;
  for (int e=lane;e<Bsz*96;e+=64) corr[e]=corr0[e];
  double wv=(double)w[n];
  double wsum=wv;
  { double v=wsum;
    v += __shfl_xor(v,1,64); v += __shfl_xor(v,2,64); v += __shfl_xor(v,4,64);
    v += __shfl_xor(v,8,64); v += __shfl_xor(v,16,64); wsum=v; }
  double mk[15];
  for (int e=0;e<15;e++) mk[e]=(double)mkp[e*Npts+n];
  double Bm[15];
  for (int e=0;e<15;e++){
    double v=mk[e]*wv;
    v += __shfl_xor(v,1,64); v += __shfl_xor(v,2,64); v += __shfl_xor(v,4,64);
    v += __shfl_xor(v,8,64); v += __shfl_xor(v,16,64);
    Bm[e]=v/wsum;
  }
  double Bc_n[15];
  for (int e=0;e<15;e++) Bc_n[e]=mk[e]-Bm[e];
  double lam=(double)lamp[0];
  double G[Kb][Kb];
  for (int k=0;k<Kb;k++) for (int l=0;l<Kb;l++){
    double p=(Bc_n[k*3+0]*Bc_n[l*3+0]+Bc_n[k*3+1]*Bc_n[l*3+1]+Bc_n[k*3+2]*Bc_n[l*3+2])*wv;
    p += __shfl_xor(p,1,64); p += __shfl_xor(p,2,64); p += __shfl_xor(p,4,64);
    p += __shfl_xor(p,8,64); p += __shfl_xor(p,16,64);
    G[k][l]=p+((k==l)?lam:0.0);
  }
  // Gauss-Jordan inverse (redundant on all lanes; uniform data)
  double Aug[Kb][2*Kb];
  for (int i=0;i<Kb;i++) for (int j=0;j<Kb;j++){ Aug[i][j]=G[i][j]; Aug[i][Kb+j]=(i==j)?1.0:0.0; }
  for (int col=0;col<Kb;col++){
    int piv=col; double best=fabs(Aug[col][col]);
    for (int r=col+1;r<Kb;r++) if (fabs(Aug[r][col])>best){best=fabs(Aug[r][col]);piv=r;}
    if (piv!=col) for (int j=0;j<2*Kb;j++){ double t=Aug[col][j]; Aug[col][j]=Aug[piv][j]; Aug[piv][j]=t; }
    double ip=1.0/Aug[col][col];
    for (int j=0;j<2*Kb;j++) Aug[col][j]*=ip;
    for (int r=0;r<Kb;r++) if (r!=col){
      double f=Aug[r][col];
      for (int j=0;j<2*Kb;j++) Aug[r][j]-=f*Aug[col][j];
    }
  }
  if (lane<32){
    consts[CD_WD+n]=(float)wv;
    for (int e=0;e<15;e++) consts[CD_BC+e*Npts+n]=(float)Bc_n[e];
  }
  if (lane==0){
    consts[CD_WSUM]=(float)wsum;
    consts[CD_LAMK]=(float)(lam/(double)Kb);
    for (int e=0;e<15;e++) consts[CD_BMEAN+e]=(float)Bm[e];
    for (int k=0;k<Kb;k++) for (int l=0;l<Kb;l++) consts[CD_GI+k*Kb+l]=(float)Aug[k][Kb+l];
  }
}

__global__ __launch_bounds__(256,1) void k_pace(const float* __restrict__ kp, const float* __restrict__ cad,
                      const float* __restrict__ corr, const float* __restrict__ consts,
                      float* __restrict__ sav_all, float* __restrict__ model,
                      u64* __restrict__ minbuf)
{
  int b=blockIdx.x, tid=threadIdx.x;
  __shared__ float sR[9], sT[3], sC[Kb];
  if (tid<64){
    int lane=tid, n=lane&31;
    float y[3];
    for (int i=0;i<3;i++)
      y[i]=kp[b*96+i*Npts+n]+corr[b*96+i*Npts+n];
    float R3[3][3],tv[3],cc[Kb];
    pace_fwd_wave(y,consts,sav_all+(size_t)b*SV_STRIDE,lane,1,R3,tv,cc);
    if (lane==0){
      for (int i=0;i<3;i++){ sT[i]=tv[i]; for (int j=0;j<3;j++) sR[i*3+j]=R3[i][j]; }
      for (int k=0;k<Kb;k++) sC[k]=cc[k];
    }
  }
  __syncthreads();
  for (int j=tid;j<NCAD;j+=256){
    float m0=0.f,m1=0.f,m2=0.f;
    for (int k=0;k<Kb;k++){
      m0+=sC[k]*cad[(k*3+0)*NCAD+j];
      m1+=sC[k]*cad[(k*3+1)*NCAD+j];
      m2+=sC[k]*cad[(k*3+2)*NCAD+j];
    }
    model[(b*3+0)*NCAD+j]=sR[0]*m0+sR[1]*m1+sR[2]*m2+sT[0];
    model[(b*3+1)*NCAD+j]=sR[3]*m0+sR[4]*m1+sR[5]*m2+sT[1];
    model[(b*3+2)*NCAD+j]=sR[6]*m0+sR[7]*m1+sR[8]*m2+sT[2];
  }
  for (int i=tid;i<Mpc;i+=256) minbuf[b*Mpc+i]=~0ull;
}

__global__ void k_chamfer(const float* __restrict__ pc, const float* __restrict__ model,
                          u64* __restrict__ minbuf)
{
  int b=blockIdx.z;
  int jbase=blockIdx.y*256;
  int ibase=blockIdx.x*512;
  int t=threadIdx.x;
  __shared__ float mx[256],my[256],mz[256];
  mx[t]=model[(b*3+0)*NCAD+jbase+t];
  my[t]=model[(b*3+1)*NCAD+jbase+t];
  mz[t]=model[(b*3+2)*NCAD+jbase+t];
  __syncthreads();
  int i0=ibase+t, i1=i0+256;
  float x0=pc[(b*3+0)*Mpc+i0], y0=pc[(b*3+1)*Mpc+i0], z0=pc[(b*3+2)*Mpc+i0];
  float x1=pc[(b*3+0)*Mpc+i1], y1=pc[(b*3+1)*Mpc+i1], z1=pc[(b*3+2)*Mpc+i1];
  float d0b=3.4e38f, d1b=3.4e38f;
  int j0=0, j1=0;
  #pragma unroll 4
  for (int j=0;j<256;j++){
    float ax=mx[j], ay=my[j], az=mz[j];
    float dx=x0-ax, dy=y0-ay, dz=z0-az;
    float d2=dx*dx+dy*dy+dz*dz;
    if (d2<d0b){d0b=d2;j0=j;}
    dx=x1-ax; dy=y1-ay; dz=z1-az;
    d2=dx*dx+dy*dy+dz*dz;
    if (d2<d1b){d1b=d2;j1=j;}
  }
  atomicMin(&minbuf[b*Mpc+i0], ((u64)__float_as_uint(d0b)<<32)|(u64)(unsigned)(jbase+j0));
  atomicMin(&minbuf[b*Mpc+i1], ((u64)__float_as_uint(d1b)<<32)|(u64)(unsigned)(jbase+j1));
}

__global__ __launch_bounds__(512,1) void k_update(const float* __restrict__ pc, const float* __restrict__ kp,
                        const float* __restrict__ cad, float* __restrict__ model,
                        u64* __restrict__ minbuf, const float* __restrict__ consts,
                        float* __restrict__ sav_all, float* __restrict__ corr,
                        float* __restrict__ out, int last)
{
  int b=blockIdx.x, tid=threadIdx.x;
  float* sav=sav_all+(size_t)b*SV_STRIDE;
  __shared__ float dmx[NCAD], dmy[NCAD], dmz[NCAD];
  __shared__ float s_part[8][17];
  __shared__ float sR[9], sT[3], sC[Kb];

  for (int j=tid;j<NCAD;j+=512){ dmx[j]=0.f; dmy[j]=0.f; dmz[j]=0.f; }
  __syncthreads();
  for (int i=tid;i<Mpc;i+=512){
    u64 key=minbuf[b*Mpc+i];
    int j=(int)(key&0xffffffffULL);
    float px=pc[(b*3+0)*Mpc+i], py=pc[(b*3+1)*Mpc+i], pz=pc[(b*3+2)*Mpc+i];
    atomicAdd(&dmx[j], model[(b*3+0)*NCAD+j]-px);
    atomicAdd(&dmy[j], model[(b*3+1)*NCAD+j]-py);
    atomicAdd(&dmz[j], model[(b*3+2)*NCAD+j]-pz);
  }
  __syncthreads();

  float cR[9], cC[Kb];
  for (int e=0;e<9;e++) cR[e]=sav[SV_R1+18+e];
  for (int k=0;k<Kb;k++) cC[k]=sav[SV_C2+k];
  float vals[17];
  for (int v=0;v<17;v++) vals[v]=0.f;
  for (int j=tid;j<NCAD;j+=512){
    float d0=dmx[j], d1=dmy[j], d2v=dmz[j];
    float cv[15];
    for (int e=0;e<15;e++) cv[e]=cad[e*NCAD+j];
    float m00=0.f,m01=0.f,m02=0.f;
    for (int k=0;k<Kb;k++){ m00+=cC[k]*cv[k*3+0]; m01+=cC[k]*cv[k*3+1]; m02+=cC[k]*cv[k*3+2]; }
    vals[0]+=d0; vals[1]+=d1; vals[2]+=d2v;
    vals[3]+=d0*m00; vals[4]+=d0*m01; vals[5]+=d0*m02;
    vals[6]+=d1*m00; vals[7]+=d1*m01; vals[8]+=d1*m02;
    vals[9]+=d2v*m00; vals[10]+=d2v*m01; vals[11]+=d2v*m02;
    float t0=cR[0]*d0+cR[3]*d1+cR[6]*d2v;
    float t1=cR[1]*d0+cR[4]*d1+cR[7]*d2v;
    float t2=cR[2]*d0+cR[5]*d1+cR[8]*d2v;
    for (int k=0;k<Kb;k++) vals[12+k]+=t0*cv[k*3+0]+t1*cv[k*3+1]+t2*cv[k*3+2];
  }
  for (int m=1;m<64;m<<=1)
    for (int v=0;v<17;v++) vals[v]+=__shfl_xor(vals[v],m,64);
  int wv=tid>>6;
  if ((tid&63)==0) for (int v=0;v<17;v++) s_part[wv][v]=vals[v];
  __syncthreads();

  if (tid<64){
    int lane=tid, n=lane&31;
    float red[17];
    for (int v=0;v<17;v++){
      float a=0.f;
      for (int w=0;w<8;w++) a+=s_part[w][v];
      red[v]=a*(2.0f/(float)Mpc);
    }
    float dy[3];
    pace_bwd_wave(red,consts,sav,lane,dy);
    float newc[3];
    for (int i=0;i<3;i++){
      float oc=corr[b*96+i*Npts+n];
      newc[i]=oc-0.5f*dy[i];
      if (lane<32) corr[b*96+i*Npts+n]=newc[i];
    }
    float y[3];
    for (int i=0;i<3;i++) y[i]=kp[b*96+i*Npts+n]+newc[i];
    float R3[3][3],tv[3],cc[Kb];
    pace_fwd_wave(y,consts,sav,lane,last?0:1,R3,tv,cc);
    if (!last){
      if (lane==0){
        for (int i=0;i<3;i++){ sT[i]=tv[i]; for (int j=0;j<3;j++) sR[i*3+j]=R3[i][j]; }
        for (int k=0;k<Kb;k++) sC[k]=cc[k];
      }
    } else {
      if (lane==0){
        for (int i=0;i<3;i++) for (int j=0;j<3;j++) out[b*9+i*3+j]=R3[i][j];
        for (int i=0;i<3;i++) out[72+b*3+i]=tv[i];
        for (int k=0;k<Kb;k++) out[96+b*Kb+k]=cc[k];
      }
      if (lane<32){
        for (int i=0;i<3;i++){
          out[136+b*96+i*Npts+n]=newc[i];
          out[904+b*96+i*Npts+n]=kp[b*96+i*Npts+n]+newc[i];
        }
      }
    }
  }
  if (!last){
    __syncthreads();
    for (int j=tid;j<NCAD;j+=512){
      float m0=0.f,m1=0.f,m2=0.f;
      for (int k=0;k<Kb;k++){
        m0+=sC[k]*cad[(k*3+0)*NCAD+j];
        m1+=sC[k]*cad[(k*3+1)*NCAD+j];
        m2+=sC[k]*cad[(k*3+2)*NCAD+j];
      }
      model[(b*3+0)*NCAD+j]=sR[0]*m0+sR[1]*m1+sR[2]*m2+sT[0];
      model[(b*3+1)*NCAD+j]=sR[3]*m0+sR[4]*m1+sR[5]*m2+sT[1];
      model[(b*3+2)*NCAD+j]=sR[6]*m0+sR[7]*m1+sR[8]*m2+sT[2];
    }
    for (int i=tid;i<Mpc;i+=512) minbuf[b*Mpc+i]=~0ull;
  }
}

extern "C" void kernel_launch(void* const* d_in, const int* in_sizes, int n_in,
                              void* d_out, int out_size, void* d_ws, size_t ws_size,
                              hipStream_t stream) {
  const float* pc   =(const float*)d_in[0];
  const float* kp   =(const float*)d_in[1];
  const float* corr0=(const float*)d_in[2];
  const float* mkp  =(const float*)d_in[3];
  const float* cad  =(const float*)d_in[4];
  const float* w    =(const float*)d_in[5];
  const float* lam  =(const float*)d_in[6];
  float* out=(float*)d_out;
  char* ws=(char*)d_ws;
  float*  corr   =(float*)(ws+0);          // 768 floats
  float*  consts =(float*)(ws+4096);       // 560 floats
  float*  sav    =(float*)(ws+8192);       // 8*512 floats
  float*  model  =(float*)(ws+45056);      // 8*3*2048 floats
  u64*    minbuf =(u64*)(ws+241664);       // 8*4096 u64

  hipLaunchKernelGGL(k_setup, dim3(1), dim3(64), 0, stream, corr0, mkp, w, lam, corr, consts);
  hipLaunchKernelGGL(k_pace, dim3(Bsz), dim3(256), 0, stream,
                     kp, cad, corr, consts, sav, model, minbuf);
  for (int s=0; s<NSTEPS; ++s){
    hipLaunchKernelGGL(k_chamfer, dim3(8,8,8), dim3(256), 0, stream, pc, model, minbuf);
    hipLaunchKernelGGL(k_update, dim3(Bsz), dim3(512), 0, stream,
                       pc, kp, cad, model, minbuf, consts, sav, corr, out, (s==NSTEPS-1)?1:0);
  }
}

// Round 6
// 1039.167 us; speedup vs baseline: 5.3458x; 1.1825x over previous
//
#include <hip/hip_runtime.h>

typedef unsigned long long u64;

#define Bsz 8
#define Npts 32
#define Kb 5
#define Mpc 4096
#define NCAD 2048
#define NSTEPS 20
#define NCHUNK 32          // chunks per batch
#define PPB 128            // points per chamfer block

// consts (floats) layout
#define CD_GI 0      // 25
#define CD_BMEAN 25  // 15
#define CD_WD 40     // 32
#define CD_WSUM 72
#define CD_LAMK 74
#define CD_BC 80     // 480
// sav per-b layout (floats), stride 512
#define SV_YC 0      // 96
#define SV_B1 96     // 3 x 96
#define SV_R1 384    // 3 x 9
#define SV_U1 411    // 3 x 22 (U9,s3,V9,d1)
#define SV_C2 477    // 5
#define SV_STRIDE 512
#define SV_USTR 22

// ---------- wave-half (32-lane) butterfly sum; lanes 32..63 mirror 0..31 ----------
__device__ __forceinline__ float wsum32(float v){
  v += __shfl_xor(v, 1, 64);
  v += __shfl_xor(v, 2, 64);
  v += __shfl_xor(v, 4, 64);
  v += __shfl_xor(v, 8, 64);
  v += __shfl_xor(v,16, 64);
  return v;
}

// ---------------- fp32 3x3 helpers (uniform data on all lanes) ----------------
__device__ __forceinline__ float det3f(const float M[3][3]){
  return M[0][0]*(M[1][1]*M[2][2]-M[1][2]*M[2][1])
       - M[0][1]*(M[1][0]*M[2][2]-M[1][2]*M[2][0])
       + M[0][2]*(M[1][0]*M[2][1]-M[1][1]*M[2][0]);
}

#define JROTF(p,q,u) { \
  float apq=A[p][q]; \
  if (fabsf(apq)>1e-30f){ \
    float theta=(A[q][q]-A[p][p])/(2.0f*apq); \
    float tt=(theta>=0.0f)?1.0f/(theta+sqrtf(1.0f+theta*theta)):1.0f/(theta-sqrtf(1.0f+theta*theta)); \
    float cc=1.0f/sqrtf(1.0f+tt*tt), ssn=tt*cc; \
    float app=A[p][p], aqq=A[q][q]; \
    A[p][p]=app-tt*apq; A[q][q]=aqq+tt*apq; A[p][q]=0.0f; A[q][p]=0.0f; \
    float aup=A[u][p], auq=A[u][q]; \
    A[u][p]=cc*aup-ssn*auq; A[p][u]=A[u][p]; \
    A[u][q]=ssn*aup+cc*auq; A[q][u]=A[u][q]; \
    for (int i_=0;i_<3;i_++){ float vip=V[i_][p], viq=V[i_][q]; V[i_][p]=cc*vip-ssn*viq; V[i_][q]=ssn*vip+cc*viq; } \
  } }

__device__ void svd3f(const float H[3][3], float U[3][3], float s[3], float V[3][3], float* dsg)
{
  float A[3][3];
  for (int i=0;i<3;i++) for (int j=0;j<3;j++){
    float a=0.0f;
    for (int k=0;k<3;k++) a += H[k][i]*H[k][j];
    A[i][j]=a;
  }
  V[0][0]=1;V[0][1]=0;V[0][2]=0; V[1][0]=0;V[1][1]=1;V[1][2]=0; V[2][0]=0;V[2][1]=0;V[2][2]=1;
  for (int sweep=0; sweep<6; ++sweep){
    float off=fabsf(A[0][1])+fabsf(A[0][2])+fabsf(A[1][2]);
    float dia=fabsf(A[0][0])+fabsf(A[1][1])+fabsf(A[2][2]);
    if (off <= 3e-7f*dia + 1e-30f) break;
    JROTF(0,1,2)
    JROTF(0,2,1)
    JROTF(1,2,0)
  }
  float e0=A[0][0], e1=A[1][1], e2=A[2][2];
  if (e0<e1){ float t=e0;e0=e1;e1=t; for(int i=0;i<3;i++){float tv=V[i][0];V[i][0]=V[i][1];V[i][1]=tv;} }
  if (e0<e2){ float t=e0;e0=e2;e2=t; for(int i=0;i<3;i++){float tv=V[i][0];V[i][0]=V[i][2];V[i][2]=tv;} }
  if (e1<e2){ float t=e1;e1=e2;e2=t; for(int i=0;i<3;i++){float tv=V[i][1];V[i][1]=V[i][2];V[i][2]=tv;} }
  for (int c=0;c<3;c++){
    float u0=H[0][0]*V[0][c]+H[0][1]*V[1][c]+H[0][2]*V[2][c];
    float u1=H[1][0]*V[0][c]+H[1][1]*V[1][c]+H[1][2]*V[2][c];
    float u2=H[2][0]*V[0][c]+H[2][1]*V[1][c]+H[2][2]*V[2][c];
    float nr=sqrtf(u0*u0+u1*u1+u2*u2);
    s[c]=nr;
    float inv=(nr>1e-30f)?1.0f/nr:0.0f;
    U[0][c]=u0*inv; U[1][c]=u1*inv; U[2][c]=u2*inv;
  }
  if (s[2] <= 1e-6f*s[0]){
    U[0][2]=U[1][0]*U[2][1]-U[2][0]*U[1][1];
    U[1][2]=U[2][0]*U[0][1]-U[0][0]*U[2][1];
    U[2][2]=U[0][0]*U[1][1]-U[1][0]*U[0][1];
  }
  float dd=det3f(U)*det3f(V);
  *dsg = (dd>=0.0f)?1.0f:-1.0f;
}

// VJP of R = U diag(1,1,d) V^T
__device__ void proc_bwd(const float dRm[3][3], const float* sv, float dH[3][3])
{
  float U[3][3],V[3][3],s[3],dsg;
  for (int i=0;i<3;i++) for (int j=0;j<3;j++){ U[i][j]=sv[i*3+j]; V[i][j]=sv[12+i*3+j]; }
  s[0]=sv[9]; s[1]=sv[10]; s[2]=sv[11];
  dsg=sv[21];
  float A0[3][3];
  for (int a=0;a<3;a++) for (int c=0;c<3;c++){
    float x=0.0f;
    for (int i=0;i<3;i++) for (int j=0;j<3;j++) x += U[i][a]*dRm[i][j]*V[j][c];
    A0[a][c]=x;
  }
  float D[3]={1.0f,1.0f,dsg};
  float Q[3][3]={{0,0,0},{0,0,0},{0,0,0}};
  for (int i=0;i<3;i++) for (int j=0;j<3;j++){
    if (i==j) continue;
    float Muu=A0[i][j]*D[j]-D[i]*A0[j][i];
    float Mvv=A0[j][i]*D[j]-D[i]*A0[i][j];
    float den=s[j]*s[j]-s[i]*s[i];
    if (fabsf(den)<1e-18f) den=(den>=0.0f?1e-18f:-1e-18f);
    Q[i][j]=(Muu*s[j]+s[i]*Mvv)/den;
  }
  for (int i=0;i<3;i++) for (int j=0;j<3;j++){
    float x=0.0f;
    for (int a=0;a<3;a++) for (int c=0;c<3;c++) x += U[i][a]*Q[a][c]*V[j][c];
    dH[i][j]=x;
  }
}

// ---------------- wave-parallel PACE forward (one wave, lane n = point lane&31) ----------------
__device__ void pace_fwd_wave(const float y[3], const float* consts, float* sav,
                              int lane, int save,
                              float R3[3][3], float tvec[3], float cout[Kb])
{
  int n = lane & 31;
  const float* Gi=consts+CD_GI;
  const float* Bmean=consts+CD_BMEAN;
  float wsum=consts[CD_WSUM], lamK=consts[CD_LAMK];
  float wd_n=consts[CD_WD+n];
  float Bc_n[15];
  for (int e=0;e<15;e++) Bc_n[e]=consts[CD_BC+e*Npts+n];

  float ymean[3], yc[3];
  for (int i=0;i<3;i++) ymean[i]=wsum32(y[i]*wd_n)/wsum;
  for (int i=0;i<3;i++) yc[i]=y[i]-ymean[i];
  if (save && lane<32) for (int i=0;i<3;i++) sav[SV_YC+i*Npts+n]=yc[i];

  float c[Kb];
  for (int k=0;k<Kb;k++) c[k]=1.0f/(float)Kb;

  for (int r=0;r<3;r++){
    float bb[3];
    for (int i=0;i<3;i++){
      float a=0.0f;
      for (int k=0;k<Kb;k++) a+=c[k]*Bc_n[k*3+i];
      bb[i]=a;
    }
    float H[3][3];
    for (int i=0;i<3;i++){
      float wy=yc[i]*wd_n;
      for (int j=0;j<3;j++) H[i][j]=wsum32(wy*bb[j]);
    }
    float U[3][3],V[3][3],s[3],dsg;
    svd3f(H,U,s,V,&dsg);
    float R[3][3];
    for (int i=0;i<3;i++) for (int j=0;j<3;j++)
      R[i][j]=U[i][0]*V[j][0]+U[i][1]*V[j][1]+dsg*U[i][2]*V[j][2];

    if (save){
      if (lane<32) for (int i=0;i<3;i++) sav[SV_B1+r*96+i*Npts+n]=bb[i];
      if (lane==0){
        float* pr=sav+SV_R1+r*9;
        for (int i=0;i<3;i++) for (int j=0;j<3;j++) pr[i*3+j]=R[i][j];
        float* pu=sav+SV_U1+r*SV_USTR;
        for (int i=0;i<3;i++) for (int j=0;j<3;j++){ pu[i*3+j]=U[i][j]; pu[12+i*3+j]=V[i][j]; }
        pu[9]=s[0]; pu[10]=s[1]; pu[11]=s[2]; pu[21]=dsg;
      }
    }

    if (r<2){
      float yr[3];
      for (int i=0;i<3;i++) yr[i]=R[0][i]*yc[0]+R[1][i]*yc[1]+R[2][i]*yc[2];
      float h[Kb];
      for (int k=0;k<Kb;k++){
        float p=(Bc_n[k*3+0]*yr[0]+Bc_n[k*3+1]*yr[1]+Bc_n[k*3+2]*yr[2])*wd_n;
        h[k]=wsum32(p)+lamK;
      }
      for (int k=0;k<Kb;k++){
        float a=0.0f;
        for (int l=0;l<Kb;l++) a+=Gi[k*Kb+l]*h[l];
        c[k]=a;
      }
    } else {
      for (int i=0;i<3;i++) for (int j=0;j<3;j++) R3[i][j]=R[i][j];
    }
  }
  float bmean[3];
  for (int i=0;i<3;i++){
    float a=0.0f;
    for (int k=0;k<Kb;k++) a+=c[k]*Bmean[k*3+i];
    bmean[i]=a;
  }
  for (int i=0;i<3;i++)
    tvec[i]=ymean[i]-(R3[i][0]*bmean[0]+R3[i][1]*bmean[1]+R3[i][2]*bmean[2]);
  for (int k=0;k<Kb;k++) cout[k]=c[k];
  if (save && lane==0) for (int k=0;k<Kb;k++) sav[SV_C2+k]=c[k];
}

// ---------------- wave-parallel PACE backward ----------------
__device__ void pace_bwd_wave(const float red[17], const float* consts, const float* sav,
                              int lane, float dy[3])
{
  int n = lane & 31;
  const float* Gi=consts+CD_GI;
  const float* Bmean=consts+CD_BMEAN;
  float wsum=consts[CD_WSUM];
  float wd_n=consts[CD_WD+n];
  float Bc_n[15];
  for (int e=0;e<15;e++) Bc_n[e]=consts[CD_BC+e*Npts+n];
  float yc[3], b0v[3], b1v[3], b2v[3];
  for (int i=0;i<3;i++){
    yc[i] =sav[SV_YC+i*Npts+n];
    b0v[i]=sav[SV_B1+0*96+i*Npts+n];
    b1v[i]=sav[SV_B1+1*96+i*Npts+n];
    b2v[i]=sav[SV_B1+2*96+i*Npts+n];
  }
  float c2[Kb];
  for (int k=0;k<Kb;k++) c2[k]=sav[SV_C2+k];
  float R3[3][3];
  for (int i=0;i<3;i++) for (int j=0;j<3;j++) R3[i][j]=sav[SV_R1+18+i*3+j];

  float dt[3]={red[0],red[1],red[2]};
  float dRm[3][3];
  for (int i=0;i<3;i++) for (int j=0;j<3;j++) dRm[i][j]=red[3+i*3+j];
  float dc[Kb];
  for (int k=0;k<Kb;k++) dc[k]=red[12+k];

  float bmean[3];
  for (int i=0;i<3;i++){ float a=0.0f; for (int k=0;k<Kb;k++) a+=c2[k]*Bmean[k*3+i]; bmean[i]=a; }
  for (int i=0;i<3;i++) for (int j=0;j<3;j++) dRm[i][j]-=dt[i]*bmean[j];
  float dbm[3];
  for (int i=0;i<3;i++) dbm[i]=-(R3[0][i]*dt[0]+R3[1][i]*dt[1]+R3[2][i]*dt[2]);
  for (int k=0;k<Kb;k++) dc[k]+=dbm[0]*Bmean[k*3+0]+dbm[1]*Bmean[k*3+1]+dbm[2]*Bmean[k*3+2];

  float dH[3][3];
  proc_bwd(dRm, sav+SV_U1+2*SV_USTR, dH);
  float dyc[3];
  for (int i=0;i<3;i++)
    dyc[i]=wd_n*(dH[i][0]*b2v[0]+dH[i][1]*b2v[1]+dH[i][2]*b2v[2]);
  {
    float dcp[Kb]={0,0,0,0,0};
    for (int j=0;j<3;j++){
      float db=wd_n*(dH[0][j]*yc[0]+dH[1][j]*yc[1]+dH[2][j]*yc[2]);
      for (int k=0;k<Kb;k++) dcp[k]+=db*Bc_n[k*3+j];
    }
    for (int k=0;k<Kb;k++) dc[k]+=wsum32(dcp[k]);
  }
  #pragma unroll
  for (int it=1; it>=0; --it){
    float dh[Kb];
    for (int k=0;k<Kb;k++){ float a=0.0f; for (int l=0;l<Kb;l++) a+=Gi[k*Kb+l]*dc[l]; dh[k]=a; }
    float dyr[3];
    for (int i=0;i<3;i++){
      float a=0.0f;
      for (int k=0;k<Kb;k++) a+=dh[k]*Bc_n[k*3+i];
      dyr[i]=wd_n*a;
    }
    float dR2[3][3];
    for (int j=0;j<3;j++) for (int i=0;i<3;i++) dR2[j][i]=wsum32(yc[j]*dyr[i]);
    float Rr[9];
    for (int e=0;e<9;e++) Rr[e]=sav[SV_R1+it*9+e];
    for (int j=0;j<3;j++) dyc[j]+=Rr[j*3+0]*dyr[0]+Rr[j*3+1]*dyr[1]+Rr[j*3+2]*dyr[2];
    proc_bwd(dR2, sav+SV_U1+it*SV_USTR, dH);
    float bs0,bs1,bs2;
    if (it==1){ bs0=b1v[0]; bs1=b1v[1]; bs2=b1v[2]; }
    else      { bs0=b0v[0]; bs1=b0v[1]; bs2=b0v[2]; }
    for (int i=0;i<3;i++) dyc[i]+=wd_n*(dH[i][0]*bs0+dH[i][1]*bs1+dH[i][2]*bs2);
    if (it>0){
      float dcp[Kb]={0,0,0,0,0};
      for (int j=0;j<3;j++){
        float db=wd_n*(dH[0][j]*yc[0]+dH[1][j]*yc[1]+dH[2][j]*yc[2]);
        for (int k=0;k<Kb;k++) dcp[k]+=db*Bc_n[k*3+j];
      }
      for (int k=0;k<Kb;k++) dc[k]=wsum32(dcp[k]);
    }
  }
  for (int i=0;i<3;i++){
    float S=wsum32(dyc[i]);
    dy[i]=dyc[i]+wd_n/wsum*(dt[i]-S);
  }
}

// -------- fp64 consts computation (wave-parallel), writes float consts to dst --------
__device__ void compute_consts_wave(const float* mkp, const float* w, const float* lamp,
                                    int lane, float* dst_lds, float* dst_glob, int write_glob)
{
  int n=lane&31;
  double wv=(double)w[n];
  double wsum;
  { double v=wv;
    v += __shfl_xor(v,1,64); v += __shfl_xor(v,2,64); v += __shfl_xor(v,4,64);
    v += __shfl_xor(v,8,64); v += __shfl_xor(v,16,64); wsum=v; }
  double mk[15];
  for (int e=0;e<15;e++) mk[e]=(double)mkp[e*Npts+n];
  double Bm[15];
  for (int e=0;e<15;e++){
    double v=mk[e]*wv;
    v += __shfl_xor(v,1,64); v += __shfl_xor(v,2,64); v += __shfl_xor(v,4,64);
    v += __shfl_xor(v,8,64); v += __shfl_xor(v,16,64);
    Bm[e]=v/wsum;
  }
  double Bc_n[15];
  for (int e=0;e<15;e++) Bc_n[e]=mk[e]-Bm[e];
  double lam=(double)lamp[0];
  double G[Kb][Kb];
  for (int k=0;k<Kb;k++) for (int l=0;l<Kb;l++){
    double p=(Bc_n[k*3+0]*Bc_n[l*3+0]+Bc_n[k*3+1]*Bc_n[l*3+1]+Bc_n[k*3+2]*Bc_n[l*3+2])*wv;
    p += __shfl_xor(p,1,64); p += __shfl_xor(p,2,64); p += __shfl_xor(p,4,64);
    p += __shfl_xor(p,8,64); p += __shfl_xor(p,16,64);
    G[k][l]=p+((k==l)?lam:0.0);
  }
  double Aug[Kb][2*Kb];
  for (int i=0;i<Kb;i++) for (int j=0;j<Kb;j++){ Aug[i][j]=G[i][j]; Aug[i][Kb+j]=(i==j)?1.0:0.0; }
  for (int col=0;col<Kb;col++){
    int piv=col; double best=fabs(Aug[col][col]);
    for (int r=col+1;r<Kb;r++) if (fabs(Aug[r][col])>best){best=fabs(Aug[r][col]);piv=r;}
    if (piv!=col) for (int j=0;j<2*Kb;j++){ double t=Aug[col][j]; Aug[col][j]=Aug[piv][j]; Aug[piv][j]=t; }
    double ip=1.0/Aug[col][col];
    for (int j=0;j<2*Kb;j++) Aug[col][j]*=ip;
    for (int r=0;r<Kb;r++) if (r!=col){
      double f=Aug[r][col];
      for (int j=0;j<2*Kb;j++) Aug[r][j]-=f*Aug[col][j];
    }
  }
  if (lane<32){
    dst_lds[CD_WD+n]=(float)wv;
    for (int e=0;e<15;e++) dst_lds[CD_BC+e*Npts+n]=(float)Bc_n[e];
    if (write_glob){
      dst_glob[CD_WD+n]=(float)wv;
      for (int e=0;e<15;e++) dst_glob[CD_BC+e*Npts+n]=(float)Bc_n[e];
    }
  }
  if (lane==0){
    dst_lds[CD_WSUM]=(float)wsum;
    dst_lds[CD_LAMK]=(float)(lam/(double)Kb);
    for (int e=0;e<15;e++) dst_lds[CD_BMEAN+e]=(float)Bm[e];
    for (int k=0;k<Kb;k++) for (int l=0;l<Kb;l++) dst_lds[CD_GI+k*Kb+l]=(float)Aug[k][Kb+l];
    if (write_glob){
      dst_glob[CD_WSUM]=(float)wsum;
      dst_glob[CD_LAMK]=(float)(lam/(double)Kb);
      for (int e=0;e<15;e++) dst_glob[CD_BMEAN+e]=(float)Bm[e];
      for (int k=0;k<Kb;k++) for (int l=0;l<Kb;l++) dst_glob[CD_GI+k*Kb+l]=(float)Aug[k][Kb+l];
    }
  }
}

// ---------------- kernels ----------------
// k_init: 8 blocks x 64 thr. consts (block0 -> global), corr copy, initial PACE fwd -> pose+sav
__global__ void k_init(const float* __restrict__ kp, const float* __restrict__ corr0,
                       const float* __restrict__ mkp, const float* __restrict__ w,
                       const float* __restrict__ lamp,
                       float* __restrict__ corr, float* __restrict__ consts,
                       float* __restrict__ sav_all, float* __restrict__ pose)
{
  int b=blockIdx.x, lane=threadIdx.x, n=lane&31;
  __shared__ float cl[560];
  for (int e=lane;e<96;e+=64) corr[b*96+e]=corr0[b*96+e];
  compute_consts_wave(mkp, w, lamp, lane, cl, consts, b==0);
  __syncthreads();
  float y[3];
  for (int i=0;i<3;i++) y[i]=kp[b*96+i*Npts+n]+corr0[b*96+i*Npts+n];
  float R3[3][3],tv[3],cc[Kb];
  pace_fwd_wave(y, cl, sav_all+(size_t)b*SV_STRIDE, lane, 1, R3, tv, cc);
  if (lane==0){
    float* P=pose+b*20;
    for (int i=0;i<3;i++) for (int j=0;j<3;j++) P[i*3+j]=R3[i][j];
    for (int i=0;i<3;i++) P[9+i]=tv[i];
    for (int k=0;k<Kb;k++) P[12+k]=cc[k];
  }
}

// fused chamfer + direct 17-sum gradient. 256 blocks (b*32+chunk) x 256 thr.
__global__ __launch_bounds__(256,1) void k_chamfer(const float* __restrict__ pc,
                        const float* __restrict__ cad, const float* __restrict__ pose,
                        float* __restrict__ acc2)
{
  int blk=blockIdx.x;
  int b=blk>>5, chunk=blk&31;
  int tid=threadIdx.x;
  __shared__ float4 smod[NCAD];
  __shared__ float s_part[4][17];
  const float* P=pose+b*20;
  float R[9],T[3],C[Kb];
  for (int e=0;e<9;e++) R[e]=P[e];
  for (int i=0;i<3;i++) T[i]=P[9+i];
  for (int k=0;k<Kb;k++) C[k]=P[12+k];
  // build rotated model + |.|^2 into LDS
  for (int j=tid;j<NCAD;j+=256){
    float cv[15];
    for (int e=0;e<15;e++) cv[e]=cad[e*NCAD+j];
    float m0=0.f,m1=0.f,m2=0.f;
    for (int k=0;k<Kb;k++){ m0+=C[k]*cv[k*3+0]; m1+=C[k]*cv[k*3+1]; m2+=C[k]*cv[k*3+2]; }
    float ax=R[0]*m0+R[1]*m1+R[2]*m2+T[0];
    float ay=R[3]*m0+R[4]*m1+R[5]*m2+T[1];
    float az=R[6]*m0+R[7]*m1+R[8]*m2+T[2];
    smod[j]=make_float4(ax,ay,az, ax*ax+ay*ay+az*az);
  }
  __syncthreads();
  // 2 points per thread, 4 threads per point (j interleaved stride 4)
  int pr=tid>>2, q=tid&3;
  int p0=chunk*PPB+pr*2, p1=p0+1;
  const float* pcb=pc+(size_t)b*3*Mpc;
  float x0=pcb[p0], y0=pcb[Mpc+p0], z0=pcb[2*Mpc+p0];
  float x1=pcb[p1], y1=pcb[Mpc+p1], z1=pcb[2*Mpc+p1];
  float nx0=-2.f*x0, ny0=-2.f*y0, nz0=-2.f*z0;
  float nx1=-2.f*x1, ny1=-2.f*y1, nz1=-2.f*z1;
  float d0=3.4e38f, d1=3.4e38f;
  int j0=0, j1=0;
  #pragma unroll 4
  for (int it=0; it<NCAD/4; ++it){
    int j=(it<<2)|q;
    float4 m=smod[j];
    float c0=fmaf(nx0,m.x,fmaf(ny0,m.y,fmaf(nz0,m.z,m.w)));
    float c1=fmaf(nx1,m.x,fmaf(ny1,m.y,fmaf(nz1,m.z,m.w)));
    if (c0<d0){d0=c0;j0=j;}
    if (c1<d1){d1=c1;j1=j;}
  }
  // combine quarters (prefer smaller j on ties)
  #pragma unroll
  for (int m=1;m<=2;m<<=1){
    float od=__shfl_xor(d0,m,64); int oj=__shfl_xor(j0,m,64);
    if (od<d0 || (od==d0 && oj<j0)){d0=od;j0=oj;}
    od=__shfl_xor(d1,m,64); oj=__shfl_xor(j1,m,64);
    if (od<d1 || (od==d1 && oj<j1)){d1=od;j1=oj;}
  }
  // direct gradient accumulation: lane q==0 -> p0, q==1 -> p1
  float vals[17];
  for (int v=0;v<17;v++) vals[v]=0.f;
  if (q<2){
    int jm=(q==0)?j0:j1;
    float px=(q==0)?x0:x1, py=(q==0)?y0:y1, pz=(q==0)?z0:z1;
    float4 m=smod[jm];
    float md0=m.x-px, md1=m.y-py, md2=m.z-pz;
    float cv[15];
    for (int e=0;e<15;e++) cv[e]=cad[e*NCAD+jm];
    float m00=0.f,m01=0.f,m02=0.f;
    for (int k=0;k<Kb;k++){ m00+=C[k]*cv[k*3+0]; m01+=C[k]*cv[k*3+1]; m02+=C[k]*cv[k*3+2]; }
    vals[0]=md0; vals[1]=md1; vals[2]=md2;
    vals[3]=md0*m00; vals[4]=md0*m01; vals[5]=md0*m02;
    vals[6]=md1*m00; vals[7]=md1*m01; vals[8]=md1*m02;
    vals[9]=md2*m00; vals[10]=md2*m01; vals[11]=md2*m02;
    float t0=R[0]*md0+R[3]*md1+R[6]*md2;
    float t1=R[1]*md0+R[4]*md1+R[7]*md2;
    float t2=R[2]*md0+R[5]*md1+R[8]*md2;
    for (int k=0;k<Kb;k++) vals[12+k]=t0*cv[k*3+0]+t1*cv[k*3+1]+t2*cv[k*3+2];
  }
  for (int m=1;m<64;m<<=1)
    for (int v=0;v<17;v++) vals[v]+=__shfl_xor(vals[v],m,64);
  int wv=tid>>6;
  if ((tid&63)==0) for (int v=0;v<17;v++) s_part[wv][v]=vals[v];
  __syncthreads();
  if (tid<17){
    float a=s_part[0][tid]+s_part[1][tid]+s_part[2][tid]+s_part[3][tid];
    acc2[(size_t)(b*NCHUNK+chunk)*20+tid]=a;
  }
}

// PACE-only update: 8 blocks x 64 thr
__global__ void k_update(const float* __restrict__ kp, const float* __restrict__ consts,
                         const float* __restrict__ acc2, float* __restrict__ sav_all,
                         float* __restrict__ corr, float* __restrict__ pose,
                         float* __restrict__ out, int last)
{
  int b=blockIdx.x, lane=threadIdx.x, n=lane&31;
  float* sav=sav_all+(size_t)b*SV_STRIDE;
  __shared__ float s_red[17];
  if (lane<17){
    float a=0.f;
    for (int ch=0;ch<NCHUNK;ch++) a+=acc2[(size_t)(b*NCHUNK+ch)*20+lane];
    s_red[lane]=a*(2.0f/(float)Mpc);
  }
  __syncthreads();
  float red[17];
  for (int v=0;v<17;v++) red[v]=s_red[v];
  float dy[3];
  pace_bwd_wave(red,consts,sav,lane,dy);
  float newc[3];
  for (int i=0;i<3;i++){
    float oc=corr[b*96+i*Npts+n];
    newc[i]=oc-0.5f*dy[i];
    if (lane<32) corr[b*96+i*Npts+n]=newc[i];
  }
  float y[3];
  for (int i=0;i<3;i++) y[i]=kp[b*96+i*Npts+n]+newc[i];
  float R3[3][3],tv[3],cc[Kb];
  pace_fwd_wave(y,consts,sav,lane,last?0:1,R3,tv,cc);
  if (!last){
    if (lane==0){
      float* P=pose+b*20;
      for (int i=0;i<3;i++) for (int j=0;j<3;j++) P[i*3+j]=R3[i][j];
      for (int i=0;i<3;i++) P[9+i]=tv[i];
      for (int k=0;k<Kb;k++) P[12+k]=cc[k];
    }
  } else {
    if (lane==0){
      for (int i=0;i<3;i++) for (int j=0;j<3;j++) out[b*9+i*3+j]=R3[i][j];
      for (int i=0;i<3;i++) out[72+b*3+i]=tv[i];
      for (int k=0;k<Kb;k++) out[96+b*Kb+k]=cc[k];
    }
    if (lane<32){
      for (int i=0;i<3;i++){
        out[136+b*96+i*Npts+n]=newc[i];
        out[904+b*96+i*Npts+n]=kp[b*96+i*Npts+n]+newc[i];
      }
    }
  }
}

extern "C" void kernel_launch(void* const* d_in, const int* in_sizes, int n_in,
                              void* d_out, int out_size, void* d_ws, size_t ws_size,
                              hipStream_t stream) {
  const float* pc   =(const float*)d_in[0];
  const float* kp   =(const float*)d_in[1];
  const float* corr0=(const float*)d_in[2];
  const float* mkp  =(const float*)d_in[3];
  const float* cad  =(const float*)d_in[4];
  const float* w    =(const float*)d_in[5];
  const float* lam  =(const float*)d_in[6];
  float* out=(float*)d_out;
  char* ws=(char*)d_ws;
  float* corr  =(float*)(ws+0);        // 768 f
  float* consts=(float*)(ws+4096);     // 560 f
  float* sav   =(float*)(ws+8192);     // 8*512 f
  float* pose  =(float*)(ws+24576);    // 8*20 f
  float* acc2  =(float*)(ws+28672);    // 8*32*20 f

  hipLaunchKernelGGL(k_init, dim3(Bsz), dim3(64), 0, stream,
                     kp, corr0, mkp, w, lam, corr, consts, sav, pose);
  for (int s=0; s<NSTEPS; ++s){
    hipLaunchKernelGGL(k_chamfer, dim3(Bsz*NCHUNK), dim3(256), 0, stream,
                       pc, cad, pose, acc2);
    hipLaunchKernelGGL(k_update, dim3(Bsz), dim3(64), 0, stream,
                       kp, consts, acc2, sav, corr, pose, out, (s==NSTEPS-1)?1:0);
  }
}